// Round 4
// baseline (445.114 us; speedup 1.0000x reference)
//
#include <hip/hip_runtime.h>
#include <hip/hip_bf16.h>

typedef unsigned short u16;
typedef unsigned int u32;
typedef __attribute__((ext_vector_type(8))) short bf16x8;   // 8 bf16 (4 VGPRs)
typedef __attribute__((ext_vector_type(4))) float f32x4;
typedef __attribute__((ext_vector_type(4))) u16 u16x4;

__device__ __forceinline__ u16 f2bf(float f) {
    union { float f; u32 u; } v; v.f = f;
    u32 r = v.u + 0x7FFF + ((v.u >> 16) & 1);   // RNE
    return (u16)(r >> 16);
}
__device__ __forceinline__ float bf_lo(u32 u) {
    union { u32 u; float f; } v; v.u = u << 16; return v.f;
}
__device__ __forceinline__ float bf_hi(u32 u) {
    union { u32 u; float f; } v; v.u = u & 0xFFFF0000u; return v.f;
}

#define NBUK 8

// ---------------- bucketize edges by dst range (+ fused degree count) ----------------
__global__ void bucketize(const int* __restrict__ src, const int* __restrict__ dst, int E, int R2,
                          int* __restrict__ cnt, int* __restrict__ bcur,
                          int2* __restrict__ bpairs, int bcap) {
    __shared__ int lcnt[NBUK], lbase[NBUK];
    const int tid = threadIdx.x;
    if (tid < NBUK) lcnt[tid] = 0;
    __syncthreads();
    int e = blockIdx.x * 256 + tid;
    int d = 0, s = 0, b = 0, pos = 0;
    bool act = (e < E);
    if (act) {
        d = dst[e]; s = src[e];
        atomicAdd(&cnt[d], 1);
        b = d / R2;
        pos = atomicAdd(&lcnt[b], 1);
    }
    __syncthreads();
    if (tid < NBUK) lbase[tid] = atomicAdd(&bcur[tid], lcnt[tid]);
    __syncthreads();
    if (act) {
        int idx = lbase[b] + pos;
        if (idx < bcap) bpairs[(size_t)b * bcap + idx] = (int2){s, d};
    }
}

// ---------------- exclusive scan (3 kernels); scan_block also emits dinv ----------------
__global__ void scan_block(const int* __restrict__ cnt, int* __restrict__ rowptr,
                           int* __restrict__ bsum, float* __restrict__ dinv, int n) {
    __shared__ int sd[256];
    int i = blockIdx.x * 256 + threadIdx.x;
    int v = (i < n) ? cnt[i] : 0;
    if (i < n) dinv[i] = rsqrtf((float)v + 1.0f);
    sd[threadIdx.x] = v;
    __syncthreads();
    for (int off = 1; off < 256; off <<= 1) {
        int t = (threadIdx.x >= off) ? sd[threadIdx.x - off] : 0;
        __syncthreads();
        sd[threadIdx.x] += t;
        __syncthreads();
    }
    if (i < n) rowptr[i] = sd[threadIdx.x] - v;
    if (threadIdx.x == 255) bsum[blockIdx.x] = sd[255];
}

__global__ void scan_sums(int* __restrict__ bsum, int* __restrict__ rowptr, int nb, int n) {
    __shared__ int sd[512];
    int v = (threadIdx.x < nb) ? bsum[threadIdx.x] : 0;
    sd[threadIdx.x] = v;
    __syncthreads();
    for (int off = 1; off < 512; off <<= 1) {
        int t = (threadIdx.x >= off) ? sd[threadIdx.x - off] : 0;
        __syncthreads();
        sd[threadIdx.x] += t;
        __syncthreads();
    }
    if (threadIdx.x < nb) bsum[threadIdx.x] = sd[threadIdx.x] - v;
    if (threadIdx.x == 511) rowptr[n] = sd[511];
}

__global__ void scan_add(int* __restrict__ rowptr, const int* __restrict__ bsum,
                         int* __restrict__ fillc, int n) {
    int i = blockIdx.x * 256 + threadIdx.x;
    if (i < n) {
        rowptr[i] += bsum[blockIdx.x];
        fillc[i] = 0;
    }
}

// ---------------- per-bucket CSR fill; bucket = blockIdx & 7 -> XCD-local window ----------------
__global__ void fill_buckets(const int2* __restrict__ bpairs, const int* __restrict__ bcur, int bcap,
                             const int* __restrict__ rowptr, int* __restrict__ fillc,
                             int* __restrict__ srcids) {
    int b = blockIdx.x & (NBUK - 1);
    int i = (blockIdx.x >> 3) * 256 + threadIdx.x;
    int nfill = bcur[b];
    if (nfill > bcap) nfill = bcap;
    if (i < nfill) {
        int2 p = bpairs[(size_t)b * bcap + i];
        int pos = atomicAdd(&fillc[p.y], 1);
        srcids[rowptr[p.y] + pos] = p.x;
    }
}

// ---------------- weight transpose+convert (both layers in one kernel) ----------------
__global__ void conv_w2(const float* __restrict__ W1, u16* __restrict__ B1, int K1, int N1,
                        const float* __restrict__ W2, u16* __restrict__ B2, int K2, int N2) {
    int i = blockIdx.x * 256 + threadIdx.x;
    int sz1 = K1 * N1;
    if (i < sz1) {
        int n = i / K1, k = i - n * K1;
        B1[i] = f2bf(W1[(size_t)k * N1 + n]);
    } else if (i - sz1 < K2 * N2) {
        int j = i - sz1;
        int n = j / K2, k = j - n * K2;
        B2[j] = f2bf(W2[(size_t)k * N2 + n]);
    }
}

// ---------------- MFMA bf16 GEMM: G[m][n] = bf16( (A @ Bt^T)[m][n] * dinv[m] ) ----------------
template <int K, int BN, int IFR, int JFR, int WM, int WN, bool ABF16>
__launch_bounds__(256)
__global__ void gemm_mfma(const void* __restrict__ Av, const u16* __restrict__ Bt,
                          const float* __restrict__ dinv, u16* __restrict__ G, int M) {
    constexpr int BM = 128, BK = 32;
    __shared__ u16 As[BM][BK];   // 64 B rows -> conflict-free b128 frag reads
    __shared__ u16 Bs[BN][BK];
    const int tid = threadIdx.x;
    const int lane = tid & 63, wave = tid >> 6;
    const int r = lane & 15, g = lane >> 4;
    const int wm = wave % WM, wn = wave / WM;
    const int m0 = blockIdx.x * BM;

    f32x4 acc[IFR][JFR];
#pragma unroll
    for (int i = 0; i < IFR; i++)
#pragma unroll
        for (int j = 0; j < JFR; j++) acc[i][j] = (f32x4){0.f, 0.f, 0.f, 0.f};

    for (int k0 = 0; k0 < K; k0 += BK) {
#pragma unroll
        for (int p = 0; p < 4; p++) {
            int q = tid + p * 256;
            int row = q >> 3, kq = (q & 7) << 2;
            int gr = m0 + row; if (gr >= M) gr = M - 1;   // clamp; stores guarded
            if constexpr (ABF16) {
                const u16* A = (const u16*)Av;
                *(u16x4*)&As[row][kq] = *(const u16x4*)(A + (size_t)gr * K + k0 + kq);
            } else {
                const float* A = (const float*)Av;
                float4 a = *(const float4*)(A + (size_t)gr * K + k0 + kq);
                u16x4 v = { f2bf(a.x), f2bf(a.y), f2bf(a.z), f2bf(a.w) };
                *(u16x4*)&As[row][kq] = v;
            }
        }
#pragma unroll
        for (int p = 0; p < BN / 32; p++) {
            int q = tid + p * 256;
            int row = q >> 3, kq = (q & 7) << 2;
            *(u16x4*)&Bs[row][kq] = *(const u16x4*)(Bt + (size_t)row * K + k0 + kq);
        }
        __syncthreads();

        bf16x8 af[IFR], bfr[JFR];
#pragma unroll
        for (int i = 0; i < IFR; i++)
            af[i] = *(const bf16x8*)&As[wm * (IFR * 16) + i * 16 + r][g * 8];
#pragma unroll
        for (int j = 0; j < JFR; j++)
            bfr[j] = *(const bf16x8*)&Bs[wn * (JFR * 16) + j * 16 + r][g * 8];
#pragma unroll
        for (int i = 0; i < IFR; i++)
#pragma unroll
            for (int j = 0; j < JFR; j++)
                acc[i][j] = __builtin_amdgcn_mfma_f32_16x16x32_bf16(af[i], bfr[j], acc[i][j], 0, 0, 0);
        __syncthreads();
    }

    // C/D layout: col=lane&15, row=(lane>>4)*4+reg
#pragma unroll
    for (int i = 0; i < IFR; i++) {
#pragma unroll
        for (int t = 0; t < 4; t++) {
            int row = m0 + wm * (IFR * 16) + i * 16 + g * 4 + t;
            if (row < M) {
                float dn = dinv[row];
#pragma unroll
                for (int j = 0; j < JFR; j++) {
                    int col = wn * (JFR * 16) + j * 16 + r;
                    G[(size_t)row * BN + col] = f2bf(acc[i][j][t] * dn);
                }
            }
        }
    }
}

// ---------------- agg, F=128: 2 edges/wave (32-lane halves, 8B loads), 8 gathers in flight ----------------
__launch_bounds__(256)
__global__ void agg128(const uint2* __restrict__ g1, const float4* __restrict__ bias,
                       const int* __restrict__ rowptr, const int* __restrict__ srcids,
                       const float* __restrict__ dinv, uint2* __restrict__ h1, int n) {
    const int wv = threadIdx.x >> 6, lane = threadIdx.x & 63;
    const int node = blockIdx.x * 4 + wv;
    if (node >= n) return;
    const int h = lane >> 5, c = lane & 31;
    const float dn = dinv[node];
    float a0 = 0.f, a1 = 0.f, a2 = 0.f, a3 = 0.f;
    if (h == 0) {
        uint2 sv = g1[(size_t)node * 32 + c];
        a0 = bf_lo(sv.x); a1 = bf_hi(sv.x); a2 = bf_lo(sv.y); a3 = bf_hi(sv.y);
    }
    const int end = rowptr[node + 1];
    int j = rowptr[node] + h;
    for (; j + 6 < end; j += 8) {       // 4 gathers/half-wave in flight = 8 edges/wave
        int s0 = srcids[j], s1 = srcids[j + 2], s2 = srcids[j + 4], s3 = srcids[j + 6];
        uint2 v0 = g1[(size_t)s0 * 32 + c];
        uint2 v1 = g1[(size_t)s1 * 32 + c];
        uint2 v2 = g1[(size_t)s2 * 32 + c];
        uint2 v3 = g1[(size_t)s3 * 32 + c];
        a0 += (bf_lo(v0.x) + bf_lo(v1.x)) + (bf_lo(v2.x) + bf_lo(v3.x));
        a1 += (bf_hi(v0.x) + bf_hi(v1.x)) + (bf_hi(v2.x) + bf_hi(v3.x));
        a2 += (bf_lo(v0.y) + bf_lo(v1.y)) + (bf_lo(v2.y) + bf_lo(v3.y));
        a3 += (bf_hi(v0.y) + bf_hi(v1.y)) + (bf_hi(v2.y) + bf_hi(v3.y));
    }
    for (; j < end; j += 2) {
        uint2 v = g1[(size_t)srcids[j] * 32 + c];
        a0 += bf_lo(v.x); a1 += bf_hi(v.x); a2 += bf_lo(v.y); a3 += bf_hi(v.y);
    }
    a0 += __shfl_xor(a0, 32); a1 += __shfl_xor(a1, 32);
    a2 += __shfl_xor(a2, 32); a3 += __shfl_xor(a3, 32);
    if (h == 0) {
        float4 bb = bias[c];
        float r0 = fmaxf(a0 * dn + bb.x, 0.f);
        float r1 = fmaxf(a1 * dn + bb.y, 0.f);
        float r2 = fmaxf(a2 * dn + bb.z, 0.f);
        float r3 = fmaxf(a3 * dn + bb.w, 0.f);
        uint2 w;
        w.x = (u32)f2bf(r0) | ((u32)f2bf(r1) << 16);
        w.y = (u32)f2bf(r2) | ((u32)f2bf(r3) << 16);
        h1[(size_t)node * 32 + c] = w;
    }
}

// ---------------- fused agg64 + head + log_softmax ----------------
// 4 edges/wave (16-lane quarters, 8B loads); h broadcast via shfl; 40 lanes = 40 logits
__launch_bounds__(256)
__global__ void agg64out(const uint2* __restrict__ g2, const float4* __restrict__ b2,
                         const int* __restrict__ rowptr, const int* __restrict__ srcids,
                         const float* __restrict__ dinv, const float* __restrict__ Wo,
                         const float* __restrict__ bo, float* __restrict__ out, int n) {
    __shared__ float Ws[64 * 40];
    __shared__ float bs[40];
    for (int i = threadIdx.x; i < 64 * 40; i += 256) Ws[i] = Wo[i];
    if (threadIdx.x < 40) bs[threadIdx.x] = bo[threadIdx.x];
    __syncthreads();

    const int wv = threadIdx.x >> 6, lane = threadIdx.x & 63;
    const int node = blockIdx.x * 4 + wv;
    if (node >= n) return;
    const int q = lane >> 4, c = lane & 15;
    const float dn = dinv[node];
    float a0 = 0.f, a1 = 0.f, a2 = 0.f, a3 = 0.f;
    if (q == 0) {
        uint2 sv = g2[(size_t)node * 16 + c];
        a0 = bf_lo(sv.x); a1 = bf_hi(sv.x); a2 = bf_lo(sv.y); a3 = bf_hi(sv.y);
    }
    const int end = rowptr[node + 1];
    int j = rowptr[node] + q;
    for (; j + 4 < end; j += 8) {       // 2 gathers/quarter in flight = 8 edges/wave
        int s0 = srcids[j], s1 = srcids[j + 4];
        uint2 v0 = g2[(size_t)s0 * 16 + c];
        uint2 v1 = g2[(size_t)s1 * 16 + c];
        a0 += bf_lo(v0.x) + bf_lo(v1.x);
        a1 += bf_hi(v0.x) + bf_hi(v1.x);
        a2 += bf_lo(v0.y) + bf_lo(v1.y);
        a3 += bf_hi(v0.y) + bf_hi(v1.y);
    }
    for (; j < end; j += 4) {
        uint2 v = g2[(size_t)srcids[j] * 16 + c];
        a0 += bf_lo(v.x); a1 += bf_hi(v.x); a2 += bf_lo(v.y); a3 += bf_hi(v.y);
    }
    a0 += __shfl_xor(a0, 16); a1 += __shfl_xor(a1, 16);
    a2 += __shfl_xor(a2, 16); a3 += __shfl_xor(a3, 16);
    a0 += __shfl_xor(a0, 32); a1 += __shfl_xor(a1, 32);
    a2 += __shfl_xor(a2, 32); a3 += __shfl_xor(a3, 32);

    float4 bb = b2[c];
    float h0 = a0 * dn + bb.x, h1v = a1 * dn + bb.y;
    float h2v = a2 * dn + bb.z, h3v = a3 * dn + bb.w;

    // logits: lane l < 40 computes logit l; h[k] lives on lane k>>2, slot k&3
    const int lc = (lane < 40) ? lane : 39;
    float acc = 0.f;
#pragma unroll
    for (int k = 0; k < 64; k++) {
        float hv;
        if ((k & 3) == 0)      hv = __shfl(h0, k >> 2);
        else if ((k & 3) == 1) hv = __shfl(h1v, k >> 2);
        else if ((k & 3) == 2) hv = __shfl(h2v, k >> 2);
        else                   hv = __shfl(h3v, k >> 2);
        acc += hv * Ws[k * 40 + lc];
    }
    acc += bs[lc];

    float lg = (lane < 40) ? acc : -3.0e38f;
    float m = lg;
#pragma unroll
    for (int o = 32; o; o >>= 1) m = fmaxf(m, __shfl_xor(m, o));
    float ex = (lane < 40) ? expf(acc - m) : 0.f;
    float sm = ex;
#pragma unroll
    for (int o = 32; o; o >>= 1) sm += __shfl_xor(sm, o);
    float lse = m + logf(sm);
    if (lane < 40) out[(size_t)node * 40 + lane] = acc - lse;
}

extern "C" void kernel_launch(void* const* d_in, const int* in_sizes, int n_in,
                              void* d_out, int out_size, void* d_ws, size_t ws_size,
                              hipStream_t stream) {
    const float* x  = (const float*)d_in[0];
    const int*   ei = (const int*)d_in[1];
    const float* W1 = (const float*)d_in[2];
    const float* b1 = (const float*)d_in[3];
    const float* W2 = (const float*)d_in[4];
    const float* b2 = (const float*)d_in[5];
    const float* Wo = (const float*)d_in[6];
    const float* bo = (const float*)d_in[7];
    float* out = (float*)d_out;

    const int HID  = in_sizes[3];           // 128
    const int IN   = in_sizes[2] / HID;     // 256
    const int HID1 = in_sizes[5];           // 64
    const int N = in_sizes[0] / IN;         // 100000
    const int E = in_sizes[1] / 2;          // 1600000
    const int* src = ei;
    const int* dst = ei + E;

    const int R2 = (N + NBUK - 1) / NBUK;           // 12500
    const int bcap = E / NBUK + E / 64 + 1024;      // ~226K (>11 sigma headroom)

    char* ws = (char*)d_ws;
    size_t off = 0;
    auto alloc = [&](size_t bytes) -> void* {
        void* p = ws + off;
        off += (bytes + 255) / 256 * 256;
        return p;
    };
    float* dinv   = (float*)alloc((size_t)N * 4);
    int*   rowptr = (int*)alloc((size_t)(N + 1) * 4);
    int*   cnt    = (int*)alloc((size_t)N * 4);
    int*   fillc  = (int*)alloc((size_t)N * 4);
    int*   bsum   = (int*)alloc(4096);
    int*   bcur   = (int*)alloc(256);
    int*   srcids = (int*)alloc((size_t)E * 4);
    u16*   W1t    = (u16*)alloc((size_t)IN * HID * 2);     // [128][256] bf16
    u16*   W2t    = (u16*)alloc((size_t)HID * HID1 * 2);   // [64][128] bf16
    // shared region: bpairs (CSR build) then g1 (gemm1/agg128) — strictly sequential uses
    size_t sharedBytes = (size_t)NBUK * bcap * 8;
    size_t g1Bytes = (size_t)N * HID * 2;
    if (g1Bytes > sharedBytes) sharedBytes = g1Bytes;
    char*  shared = (char*)alloc(sharedBytes);
    int2*  bpairs = (int2*)shared;
    u16*   g1     = (u16*)shared;
    u16*   h1     = (u16*)alloc((size_t)N * HID * 2);      // bf16 [N][128]
    u16*   g2     = (u16*)alloc((size_t)N * HID1 * 2);     // bf16 [N][64]

    // degree + bucketed edge routing (one pass over edges)
    hipMemsetAsync(cnt, 0, (size_t)N * 4, stream);
    hipMemsetAsync(bcur, 0, NBUK * 4, stream);
    bucketize<<<(E + 255) / 256, 256, 0, stream>>>(src, dst, E, R2, cnt, bcur, bpairs, bcap);

    // CSR scan (scan_block also emits dinv; scan_add also zeroes fillc)
    int nb = (N + 255) / 256;
    scan_block<<<nb, 256, 0, stream>>>(cnt, rowptr, bsum, dinv, N);
    scan_sums<<<1, 512, 0, stream>>>(bsum, rowptr, nb, N);
    scan_add<<<nb, 256, 0, stream>>>(rowptr, bsum, fillc, N);

    // per-bucket fill: bucket = blockIdx & 7 -> XCD-local scatter window
    int fb = (bcap + 255) / 256;
    fill_buckets<<<NBUK * fb, 256, 0, stream>>>(bpairs, bcur, bcap, rowptr, fillc, srcids);

    // weights -> bf16 transposed (both in one launch)
    conv_w2<<<(IN * HID + HID * HID1 + 255) / 256, 256, 0, stream>>>(
        W1, W1t, IN, HID, W2, W2t, HID, HID1);

    const int gblocks = (N + 127) / 128;
    // layer 1: g1 = bf16((x @ W1) * dinv); h1 = bf16(relu(agg(g1)*dinv + b1))
    gemm_mfma<256, 128, 4, 4, 2, 2, false><<<gblocks, 256, 0, stream>>>(x, W1t, dinv, g1, N);
    agg128<<<(N + 3) / 4, 256, 0, stream>>>((const uint2*)g1, (const float4*)b1,
                                            rowptr, srcids, dinv, (uint2*)h1, N);

    // layer 2: g2 = bf16((h1 @ W2) * dinv); out = log_softmax((agg(g2)*dinv + b2) @ Wo + bo)
    gemm_mfma<128, 64, 2, 4, 4, 1, true><<<gblocks, 256, 0, stream>>>(h1, W2t, dinv, g2, N);
    agg64out<<<(N + 3) / 4, 256, 0, stream>>>((const uint2*)g2, (const float4*)b2,
                                              rowptr, srcids, dinv, Wo, bo, out, N);

    (void)ws_size; (void)n_in; (void)out_size; (void)HID1;
}

// Round 5
// 398.077 us; speedup vs baseline: 1.1182x; 1.1182x over previous
//
#include <hip/hip_runtime.h>
#include <hip/hip_bf16.h>

typedef unsigned short u16;
typedef unsigned int u32;
typedef __attribute__((ext_vector_type(8))) short bf16x8;   // 8 bf16 (4 VGPRs)
typedef __attribute__((ext_vector_type(4))) float f32x4;
typedef __attribute__((ext_vector_type(4))) u16 u16x4;

__device__ __forceinline__ u16 f2bf(float f) {
    union { float f; u32 u; } v; v.f = f;
    u32 r = v.u + 0x7FFF + ((v.u >> 16) & 1);   // RNE
    return (u16)(r >> 16);
}
__device__ __forceinline__ float bf_lo(u32 u) {
    union { u32 u; float f; } v; v.u = u << 16; return v.f;
}
__device__ __forceinline__ float bf_hi(u32 u) {
    union { u32 u; float f; } v; v.u = u & 0xFFFF0000u; return v.f;
}

#define NBUK 8

// ---------------- bucketize edges by dst range (+ fused degree count) ----------------
__global__ void bucketize(const int* __restrict__ src, const int* __restrict__ dst, int E, int R2,
                          int* __restrict__ cnt, int* __restrict__ bcur,
                          int2* __restrict__ bpairs, int bcap) {
    __shared__ int lcnt[NBUK], lbase[NBUK];
    const int tid = threadIdx.x;
    if (tid < NBUK) lcnt[tid] = 0;
    __syncthreads();
    int e = blockIdx.x * 256 + tid;
    int d = 0, s = 0, b = 0, pos = 0;
    bool act = (e < E);
    if (act) {
        d = dst[e]; s = src[e];
        atomicAdd(&cnt[d], 1);
        b = d / R2;
        pos = atomicAdd(&lcnt[b], 1);
    }
    __syncthreads();
    if (tid < NBUK) lbase[tid] = atomicAdd(&bcur[tid], lcnt[tid]);
    __syncthreads();
    if (act) {
        int idx = lbase[b] + pos;
        if (idx < bcap) bpairs[(size_t)b * bcap + idx] = (int2){s, d};
    }
}

// ---------------- exclusive scan (3 kernels); scan_block also emits dinv ----------------
__global__ void scan_block(const int* __restrict__ cnt, int* __restrict__ rowptr,
                           int* __restrict__ bsum, float* __restrict__ dinv, int n) {
    __shared__ int sd[256];
    int i = blockIdx.x * 256 + threadIdx.x;
    int v = (i < n) ? cnt[i] : 0;
    if (i < n) dinv[i] = rsqrtf((float)v + 1.0f);
    sd[threadIdx.x] = v;
    __syncthreads();
    for (int off = 1; off < 256; off <<= 1) {
        int t = (threadIdx.x >= off) ? sd[threadIdx.x - off] : 0;
        __syncthreads();
        sd[threadIdx.x] += t;
        __syncthreads();
    }
    if (i < n) rowptr[i] = sd[threadIdx.x] - v;
    if (threadIdx.x == 255) bsum[blockIdx.x] = sd[255];
}

__global__ void scan_sums(int* __restrict__ bsum, int* __restrict__ rowptr, int nb, int n) {
    __shared__ int sd[512];
    int v = (threadIdx.x < nb) ? bsum[threadIdx.x] : 0;
    sd[threadIdx.x] = v;
    __syncthreads();
    for (int off = 1; off < 512; off <<= 1) {
        int t = (threadIdx.x >= off) ? sd[threadIdx.x - off] : 0;
        __syncthreads();
        sd[threadIdx.x] += t;
        __syncthreads();
    }
    if (threadIdx.x < nb) bsum[threadIdx.x] = sd[threadIdx.x] - v;
    if (threadIdx.x == 511) rowptr[n] = sd[511];
}

__global__ void scan_add(int* __restrict__ rowptr, const int* __restrict__ bsum,
                         int* __restrict__ fillc, int n) {
    int i = blockIdx.x * 256 + threadIdx.x;
    if (i < n) {
        rowptr[i] += bsum[blockIdx.x];
        fillc[i] = 0;
    }
}

// ---------------- per-bucket CSR fill; bucket = blockIdx & 7 -> XCD-local window ----------------
__global__ void fill_buckets(const int2* __restrict__ bpairs, const int* __restrict__ bcur, int bcap,
                             const int* __restrict__ rowptr, int* __restrict__ fillc,
                             int* __restrict__ srcids) {
    int b = blockIdx.x & (NBUK - 1);
    int i = (blockIdx.x >> 3) * 256 + threadIdx.x;
    int nfill = bcur[b];
    if (nfill > bcap) nfill = bcap;
    if (i < nfill) {
        int2 p = bpairs[(size_t)b * bcap + i];
        int pos = atomicAdd(&fillc[p.y], 1);
        srcids[rowptr[p.y] + pos] = p.x;
    }
}

// ---------------- weight transpose+convert (both layers in one kernel) ----------------
__global__ void conv_w2(const float* __restrict__ W1, u16* __restrict__ B1, int K1, int N1,
                        const float* __restrict__ W2, u16* __restrict__ B2, int K2, int N2) {
    int i = blockIdx.x * 256 + threadIdx.x;
    int sz1 = K1 * N1;
    if (i < sz1) {
        int n = i / K1, k = i - n * K1;
        B1[i] = f2bf(W1[(size_t)k * N1 + n]);
    } else if (i - sz1 < K2 * N2) {
        int j = i - sz1;
        int n = j / K2, k = j - n * K2;
        B2[j] = f2bf(W2[(size_t)k * N2 + n]);
    }
}

// ---------------- MFMA bf16 GEMM: G[m][n] = bf16( (A @ Bt^T)[m][n] * dinv[m] ) ----------------
template <int K, int BN, int IFR, int JFR, int WM, int WN, bool ABF16>
__launch_bounds__(256)
__global__ void gemm_mfma(const void* __restrict__ Av, const u16* __restrict__ Bt,
                          const float* __restrict__ dinv, u16* __restrict__ G, int M) {
    constexpr int BM = 128, BK = 32;
    __shared__ u16 As[BM][BK];   // 64 B rows -> conflict-free b128 frag reads
    __shared__ u16 Bs[BN][BK];
    const int tid = threadIdx.x;
    const int lane = tid & 63, wave = tid >> 6;
    const int r = lane & 15, g = lane >> 4;
    const int wm = wave % WM, wn = wave / WM;
    const int m0 = blockIdx.x * BM;

    f32x4 acc[IFR][JFR];
#pragma unroll
    for (int i = 0; i < IFR; i++)
#pragma unroll
        for (int j = 0; j < JFR; j++) acc[i][j] = (f32x4){0.f, 0.f, 0.f, 0.f};

    for (int k0 = 0; k0 < K; k0 += BK) {
#pragma unroll
        for (int p = 0; p < 4; p++) {
            int q = tid + p * 256;
            int row = q >> 3, kq = (q & 7) << 2;
            int gr = m0 + row; if (gr >= M) gr = M - 1;   // clamp; stores guarded
            if constexpr (ABF16) {
                const u16* A = (const u16*)Av;
                *(u16x4*)&As[row][kq] = *(const u16x4*)(A + (size_t)gr * K + k0 + kq);
            } else {
                const float* A = (const float*)Av;
                float4 a = *(const float4*)(A + (size_t)gr * K + k0 + kq);
                u16x4 v = { f2bf(a.x), f2bf(a.y), f2bf(a.z), f2bf(a.w) };
                *(u16x4*)&As[row][kq] = v;
            }
        }
#pragma unroll
        for (int p = 0; p < BN / 32; p++) {
            int q = tid + p * 256;
            int row = q >> 3, kq = (q & 7) << 2;
            *(u16x4*)&Bs[row][kq] = *(const u16x4*)(Bt + (size_t)row * K + k0 + kq);
        }
        __syncthreads();

        bf16x8 af[IFR], bfr[JFR];
#pragma unroll
        for (int i = 0; i < IFR; i++)
            af[i] = *(const bf16x8*)&As[wm * (IFR * 16) + i * 16 + r][g * 8];
#pragma unroll
        for (int j = 0; j < JFR; j++)
            bfr[j] = *(const bf16x8*)&Bs[wn * (JFR * 16) + j * 16 + r][g * 8];
#pragma unroll
        for (int i = 0; i < IFR; i++)
#pragma unroll
            for (int j = 0; j < JFR; j++)
                acc[i][j] = __builtin_amdgcn_mfma_f32_16x16x32_bf16(af[i], bfr[j], acc[i][j], 0, 0, 0);
        __syncthreads();
    }

    // C/D layout: col=lane&15, row=(lane>>4)*4+reg
#pragma unroll
    for (int i = 0; i < IFR; i++) {
#pragma unroll
        for (int t = 0; t < 4; t++) {
            int row = m0 + wm * (IFR * 16) + i * 16 + g * 4 + t;
            if (row < M) {
                float dn = dinv[row];
#pragma unroll
                for (int j = 0; j < JFR; j++) {
                    int col = wn * (JFR * 16) + j * 16 + r;
                    G[(size_t)row * BN + col] = f2bf(acc[i][j][t] * dn);
                }
            }
        }
    }
}

// ---------------- agg, F=128: 2 edges/wave (32-lane halves, 8B loads), 16 gathers/wave in flight ----------------
__launch_bounds__(256)
__global__ void agg128(const uint2* __restrict__ g1, const float4* __restrict__ bias,
                       const int* __restrict__ rowptr, const int* __restrict__ srcids,
                       const float* __restrict__ dinv, uint2* __restrict__ h1, int n) {
    const int wv = threadIdx.x >> 6, lane = threadIdx.x & 63;
    const int node = blockIdx.x * 4 + wv;
    if (node >= n) return;
    const int h = lane >> 5, c = lane & 31;
    const float dn = dinv[node];
    float a0 = 0.f, a1 = 0.f, a2 = 0.f, a3 = 0.f;
    if (h == 0) {
        uint2 sv = g1[(size_t)node * 32 + c];
        a0 = bf_lo(sv.x); a1 = bf_hi(sv.x); a2 = bf_lo(sv.y); a3 = bf_hi(sv.y);
    }
    const int end = rowptr[node + 1];
    int j = rowptr[node] + h;
    for (; j + 14 < end; j += 16) {     // 8 gathers/half-wave in flight = 16 edges/wave
        int s0 = srcids[j],      s1 = srcids[j + 2],  s2 = srcids[j + 4],  s3 = srcids[j + 6];
        int s4 = srcids[j + 8],  s5 = srcids[j + 10], s6 = srcids[j + 12], s7 = srcids[j + 14];
        uint2 v0 = g1[(size_t)s0 * 32 + c];
        uint2 v1 = g1[(size_t)s1 * 32 + c];
        uint2 v2 = g1[(size_t)s2 * 32 + c];
        uint2 v3 = g1[(size_t)s3 * 32 + c];
        uint2 v4 = g1[(size_t)s4 * 32 + c];
        uint2 v5 = g1[(size_t)s5 * 32 + c];
        uint2 v6 = g1[(size_t)s6 * 32 + c];
        uint2 v7 = g1[(size_t)s7 * 32 + c];
        a0 += ((bf_lo(v0.x) + bf_lo(v1.x)) + (bf_lo(v2.x) + bf_lo(v3.x)))
            + ((bf_lo(v4.x) + bf_lo(v5.x)) + (bf_lo(v6.x) + bf_lo(v7.x)));
        a1 += ((bf_hi(v0.x) + bf_hi(v1.x)) + (bf_hi(v2.x) + bf_hi(v3.x)))
            + ((bf_hi(v4.x) + bf_hi(v5.x)) + (bf_hi(v6.x) + bf_hi(v7.x)));
        a2 += ((bf_lo(v0.y) + bf_lo(v1.y)) + (bf_lo(v2.y) + bf_lo(v3.y)))
            + ((bf_lo(v4.y) + bf_lo(v5.y)) + (bf_lo(v6.y) + bf_lo(v7.y)));
        a3 += ((bf_hi(v0.y) + bf_hi(v1.y)) + (bf_hi(v2.y) + bf_hi(v3.y)))
            + ((bf_hi(v4.y) + bf_hi(v5.y)) + (bf_hi(v6.y) + bf_hi(v7.y)));
    }
    for (; j < end; j += 2) {
        uint2 v = g1[(size_t)srcids[j] * 32 + c];
        a0 += bf_lo(v.x); a1 += bf_hi(v.x); a2 += bf_lo(v.y); a3 += bf_hi(v.y);
    }
    a0 += __shfl_xor(a0, 32); a1 += __shfl_xor(a1, 32);
    a2 += __shfl_xor(a2, 32); a3 += __shfl_xor(a3, 32);
    if (h == 0) {
        float4 bb = bias[c];
        float r0 = fmaxf(a0 * dn + bb.x, 0.f);
        float r1 = fmaxf(a1 * dn + bb.y, 0.f);
        float r2 = fmaxf(a2 * dn + bb.z, 0.f);
        float r3 = fmaxf(a3 * dn + bb.w, 0.f);
        uint2 w;
        w.x = (u32)f2bf(r0) | ((u32)f2bf(r1) << 16);
        w.y = (u32)f2bf(r2) | ((u32)f2bf(r3) << 16);
        h1[(size_t)node * 32 + c] = w;
    }
}

// ---------------- agg, F=64: 2 edges/wave (32-lane halves, 4B loads), 16 gathers/wave in flight ----------------
__launch_bounds__(256)
__global__ void agg64(const u32* __restrict__ g2, const float2* __restrict__ bias,
                      const int* __restrict__ rowptr, const int* __restrict__ srcids,
                      const float* __restrict__ dinv, float* __restrict__ h2, int n) {
    const int wv = threadIdx.x >> 6, lane = threadIdx.x & 63;
    const int node = blockIdx.x * 4 + wv;
    if (node >= n) return;
    const int h = lane >> 5, c = lane & 31;
    const float dn = dinv[node];
    float a0 = 0.f, a1 = 0.f;
    if (h == 0) {
        u32 sv = g2[(size_t)node * 32 + c];
        a0 = bf_lo(sv); a1 = bf_hi(sv);
    }
    const int end = rowptr[node + 1];
    int j = rowptr[node] + h;
    for (; j + 14 < end; j += 16) {     // 8 gathers/half-wave in flight = 16 edges/wave
        int s0 = srcids[j],      s1 = srcids[j + 2],  s2 = srcids[j + 4],  s3 = srcids[j + 6];
        int s4 = srcids[j + 8],  s5 = srcids[j + 10], s6 = srcids[j + 12], s7 = srcids[j + 14];
        u32 v0 = g2[(size_t)s0 * 32 + c];
        u32 v1 = g2[(size_t)s1 * 32 + c];
        u32 v2 = g2[(size_t)s2 * 32 + c];
        u32 v3 = g2[(size_t)s3 * 32 + c];
        u32 v4 = g2[(size_t)s4 * 32 + c];
        u32 v5 = g2[(size_t)s5 * 32 + c];
        u32 v6 = g2[(size_t)s6 * 32 + c];
        u32 v7 = g2[(size_t)s7 * 32 + c];
        a0 += ((bf_lo(v0) + bf_lo(v1)) + (bf_lo(v2) + bf_lo(v3)))
            + ((bf_lo(v4) + bf_lo(v5)) + (bf_lo(v6) + bf_lo(v7)));
        a1 += ((bf_hi(v0) + bf_hi(v1)) + (bf_hi(v2) + bf_hi(v3)))
            + ((bf_hi(v4) + bf_hi(v5)) + (bf_hi(v6) + bf_hi(v7)));
    }
    for (; j < end; j += 2) {
        u32 v = g2[(size_t)srcids[j] * 32 + c];
        a0 += bf_lo(v); a1 += bf_hi(v);
    }
    a0 += __shfl_xor(a0, 32);
    a1 += __shfl_xor(a1, 32);
    if (h == 0) {
        float2 bb = bias[c];
        float2 w;
        w.x = a0 * dn + bb.x;
        w.y = a1 * dn + bb.y;
        *(float2*)&h2[(size_t)node * 64 + c * 2] = w;
    }
}

// ---------------- final: out = log_softmax(h2 @ Wo + bo) ----------------
__launch_bounds__(256)
__global__ void out_kernel(const float* __restrict__ h2, const float* __restrict__ Wo,
                           const float* __restrict__ bo, float* __restrict__ out, int n) {
    __shared__ float Ws[64 * 40];
    __shared__ float bs[40];
    for (int i = threadIdx.x; i < 64 * 40; i += 256) Ws[i] = Wo[i];
    if (threadIdx.x < 40) bs[threadIdx.x] = bo[threadIdx.x];
    __syncthreads();

    int row = blockIdx.x * 256 + threadIdx.x;
    if (row >= n) return;

    float acc[40];
#pragma unroll
    for (int j = 0; j < 40; j++) acc[j] = 0.f;

    const float4* hr = (const float4*)(h2 + (size_t)row * 64);
#pragma unroll 4
    for (int k4 = 0; k4 < 16; k4++) {
        float4 h4 = hr[k4];
        float hv[4] = {h4.x, h4.y, h4.z, h4.w};
#pragma unroll
        for (int u = 0; u < 4; u++) {
            float a = hv[u];
            const float* wrow = &Ws[(k4 * 4 + u) * 40];
#pragma unroll
            for (int j = 0; j < 40; j++) acc[j] += a * wrow[j];
        }
    }

    float m = -1e30f;
#pragma unroll
    for (int j = 0; j < 40; j++) { acc[j] += bs[j]; m = fmaxf(m, acc[j]); }
    float s = 0.f;
#pragma unroll
    for (int j = 0; j < 40; j++) s += expf(acc[j] - m);
    float lse = m + logf(s);

    float* op = out + (size_t)row * 40;
#pragma unroll
    for (int j4 = 0; j4 < 10; j4++) {
        float4 w = { acc[j4 * 4] - lse, acc[j4 * 4 + 1] - lse,
                     acc[j4 * 4 + 2] - lse, acc[j4 * 4 + 3] - lse };
        *(float4*)(op + j4 * 4) = w;
    }
}

extern "C" void kernel_launch(void* const* d_in, const int* in_sizes, int n_in,
                              void* d_out, int out_size, void* d_ws, size_t ws_size,
                              hipStream_t stream) {
    const float* x  = (const float*)d_in[0];
    const int*   ei = (const int*)d_in[1];
    const float* W1 = (const float*)d_in[2];
    const float* b1 = (const float*)d_in[3];
    const float* W2 = (const float*)d_in[4];
    const float* b2 = (const float*)d_in[5];
    const float* Wo = (const float*)d_in[6];
    const float* bo = (const float*)d_in[7];
    float* out = (float*)d_out;

    const int HID  = in_sizes[3];           // 128
    const int IN   = in_sizes[2] / HID;     // 256
    const int HID1 = in_sizes[5];           // 64
    const int N = in_sizes[0] / IN;         // 100000
    const int E = in_sizes[1] / 2;          // 1600000
    const int* src = ei;
    const int* dst = ei + E;

    const int R2 = (N + NBUK - 1) / NBUK;           // 12500
    const int bcap = E / NBUK + E / 64 + 1024;      // ~226K (>11 sigma headroom)

    char* ws = (char*)d_ws;
    size_t off = 0;
    auto alloc = [&](size_t bytes) -> void* {
        void* p = ws + off;
        off += (bytes + 255) / 256 * 256;
        return p;
    };
    float* dinv   = (float*)alloc((size_t)N * 4);
    int*   rowptr = (int*)alloc((size_t)(N + 1) * 4);
    int*   cnt    = (int*)alloc((size_t)N * 4);
    int*   fillc  = (int*)alloc((size_t)N * 4);
    int*   bsum   = (int*)alloc(4096);
    int*   bcur   = (int*)alloc(256);
    int*   srcids = (int*)alloc((size_t)E * 4);
    u16*   W1t    = (u16*)alloc((size_t)IN * HID * 2);     // [128][256] bf16
    u16*   W2t    = (u16*)alloc((size_t)HID * HID1 * 2);   // [64][128] bf16
    // shared region: bpairs (CSR build) then g1 (gemm1/agg128) — strictly sequential uses
    size_t sharedBytes = (size_t)NBUK * bcap * 8;
    size_t g1Bytes = (size_t)N * HID * 2;
    if (g1Bytes > sharedBytes) sharedBytes = g1Bytes;
    char*  shared = (char*)alloc(sharedBytes);
    int2*  bpairs = (int2*)shared;
    u16*   g1     = (u16*)shared;
    u16*   h1     = (u16*)alloc((size_t)N * HID * 2);      // bf16 [N][128]
    u16*   g2     = (u16*)alloc((size_t)N * HID1 * 2);     // bf16 [N][64]
    float* h2     = (float*)alloc((size_t)N * HID1 * 4);   // fp32 [N][64]

    // degree + bucketed edge routing (one pass over edges)
    hipMemsetAsync(cnt, 0, (size_t)N * 4, stream);
    hipMemsetAsync(bcur, 0, NBUK * 4, stream);
    bucketize<<<(E + 255) / 256, 256, 0, stream>>>(src, dst, E, R2, cnt, bcur, bpairs, bcap);

    // CSR scan (scan_block also emits dinv; scan_add also zeroes fillc)
    int nb = (N + 255) / 256;
    scan_block<<<nb, 256, 0, stream>>>(cnt, rowptr, bsum, dinv, N);
    scan_sums<<<1, 512, 0, stream>>>(bsum, rowptr, nb, N);
    scan_add<<<nb, 256, 0, stream>>>(rowptr, bsum, fillc, N);

    // per-bucket fill: bucket = blockIdx & 7 -> XCD-local scatter window
    int fb = (bcap + 255) / 256;
    fill_buckets<<<NBUK * fb, 256, 0, stream>>>(bpairs, bcur, bcap, rowptr, fillc, srcids);

    // weights -> bf16 transposed (both in one launch)
    conv_w2<<<(IN * HID + HID * HID1 + 255) / 256, 256, 0, stream>>>(
        W1, W1t, IN, HID, W2, W2t, HID, HID1);

    const int gblocks = (N + 127) / 128;
    // layer 1: g1 = bf16((x @ W1) * dinv); h1 = bf16(relu(agg(g1)*dinv + b1))
    gemm_mfma<256, 128, 4, 4, 2, 2, false><<<gblocks, 256, 0, stream>>>(x, W1t, dinv, g1, N);
    agg128<<<(N + 3) / 4, 256, 0, stream>>>((const uint2*)g1, (const float4*)b1,
                                            rowptr, srcids, dinv, (uint2*)h1, N);

    // layer 2: g2 = bf16((h1 @ W2) * dinv); h2 = agg(g2)*dinv + b2 (fp32)
    gemm_mfma<128, 64, 2, 4, 4, 1, true><<<gblocks, 256, 0, stream>>>(h1, W2t, dinv, g2, N);
    agg64<<<(N + 3) / 4, 256, 0, stream>>>((const u32*)g2, (const float2*)b2,
                                           rowptr, srcids, dinv, h2, N);

    // output head + log_softmax
    out_kernel<<<(N + 255) / 256, 256, 0, stream>>>(h2, Wo, bo, out, N);
    (void)ws_size; (void)n_in; (void)out_size; (void)HID1;
}

// Round 6
// 361.952 us; speedup vs baseline: 1.2298x; 1.0998x over previous
//
#include <hip/hip_runtime.h>
#include <hip/hip_bf16.h>

typedef unsigned short u16;
typedef unsigned int u32;
typedef __attribute__((ext_vector_type(8))) short bf16x8;   // 8 bf16 (4 VGPRs)
typedef __attribute__((ext_vector_type(4))) float f32x4;
typedef __attribute__((ext_vector_type(4))) u16 u16x4;

__device__ __forceinline__ u16 f2bf(float f) {
    union { float f; u32 u; } v; v.f = f;
    u32 r = v.u + 0x7FFF + ((v.u >> 16) & 1);   // RNE
    return (u16)(r >> 16);
}
__device__ __forceinline__ float bf_lo(u32 u) {
    union { u32 u; float f; } v; v.u = u << 16; return v.f;
}
__device__ __forceinline__ float bf_hi(u32 u) {
    union { u32 u; float f; } v; v.u = u & 0xFFFF0000u; return v.f;
}

#define NB1 16     // super-buckets (stage 1)
#define NB2 128    // final buckets

// ---------------- stage 1: edges -> 16 dst-range super-buckets ----------------
// per-tile LDS counts; ONE global reservation atomic per bucket per tile; coalesced run writes
__launch_bounds__(256)
__global__ void route1(const int* __restrict__ src, const int* __restrict__ dst, int E, int R1,
                       int* __restrict__ bcur, int2* __restrict__ bp, int bcap) {
    __shared__ int lcnt[NB1], lbase[NB1];
    const int tid = threadIdx.x;
    const int ntile = (E + 255) >> 8;
    for (int t = blockIdx.x; t < ntile; t += gridDim.x) {
        if (tid < NB1) lcnt[tid] = 0;
        __syncthreads();
        int e = (t << 8) + tid;
        bool act = (e < E);
        int s = 0, d = 0, b = 0, pos = 0;
        if (act) {
            d = dst[e]; s = src[e];
            b = d / R1;
            pos = atomicAdd(&lcnt[b], 1);
        }
        __syncthreads();
        if (tid < NB1 && lcnt[tid]) lbase[tid] = atomicAdd(&bcur[tid], lcnt[tid]);
        __syncthreads();
        if (act) {
            int idx = lbase[b] + pos;
            if (idx < bcap) bp[(size_t)b * bcap + idx] = (int2){s, d};
        }
        // next iteration's first barrier protects lcnt/lbase reuse
    }
}

// ---------------- stage 2: super-bucket -> 8 final buckets each (128 total) ----------------
__launch_bounds__(256)
__global__ void route2(const int2* __restrict__ bp1, const int* __restrict__ bcnt1, int bcap1,
                       int R1, int R2, int* __restrict__ bcur2, int2* __restrict__ bp2, int bcap2) {
    __shared__ int lcnt[32], lbase[32];
    const int sb = blockIdx.x & (NB1 - 1);
    const int t = blockIdx.x >> 4;
    const int tid = threadIdx.x;
    int cnt = bcnt1[sb];
    if (cnt > bcap1) cnt = bcap1;
    if (t * 256 >= cnt) return;
    if (tid < 32) lcnt[tid] = 0;
    __syncthreads();
    const int i = t * 256 + tid;
    const int f0 = (sb * R1) / R2;
    bool act = (i < cnt);
    int2 p; int rel = 0, pos = 0;
    if (act) {
        p = bp1[(size_t)sb * bcap1 + i];
        rel = p.y / R2 - f0;                  // span <= 9 < 32
        pos = atomicAdd(&lcnt[rel], 1);
    }
    __syncthreads();
    if (tid < 32 && lcnt[tid]) lbase[tid] = atomicAdd(&bcur2[f0 + tid], lcnt[tid]);
    __syncthreads();
    if (act) {
        int idx = lbase[rel] + pos;
        if (idx < bcap2) bp2[(size_t)(f0 + rel) * bcap2 + idx] = p;
    }
}

// ---------------- exclusive scan of 128 bucket counts -> global srcids bases ----------------
__global__ void scan_vcnt(const int* __restrict__ bcnt2, int* __restrict__ vbase,
                          int* __restrict__ rowptr, int N, int E) {
    __shared__ int sd[NB2];
    const int t = threadIdx.x;
    int v = bcnt2[t];
    sd[t] = v;
    __syncthreads();
    for (int off = 1; off < NB2; off <<= 1) {
        int u = (t >= off) ? sd[t - off] : 0;
        __syncthreads();
        sd[t] += u;
        __syncthreads();
    }
    vbase[t] = sd[t] - v;   // exclusive
    if (t == NB2 - 1) rowptr[N] = E;
}

// ---------------- per-bucket CSR build: LDS histogram + scan + LDS-atomic fill ----------------
// zero per-edge global atomics; srcids writes land in a ~50KB L2-local window per block
__launch_bounds__(256)
__global__ void build_csr(const int2* __restrict__ bp2, const int* __restrict__ bcnt2, int bcap2,
                          const int* __restrict__ vbase, int R2, int N,
                          int* __restrict__ rowptr, float* __restrict__ dinv,
                          int* __restrict__ srcids) {
    __shared__ int bins[1024];       // R2 <= 1024
    __shared__ int tsum[256];
    const int b = blockIdx.x;
    const int tid = threadIdx.x;
    const int lo = b * R2;
    int hi = lo + R2; if (hi > N) hi = N;
    const int nb = hi - lo;
    if (nb <= 0) return;
    int cnt = bcnt2[b];
    if (cnt > bcap2) cnt = bcap2;
    const int2* mine = bp2 + (size_t)b * bcap2;

    for (int i = tid; i < nb; i += 256) bins[i] = 0;
    __syncthreads();
    for (int i = tid; i < cnt; i += 256) {
        int2 p = mine[i];
        atomicAdd(&bins[p.y - lo], 1);
    }
    __syncthreads();

    // per-thread 4-bin segment: local exclusive prefix + dinv
    const int base4 = tid * 4;
    int ex[4]; int run = 0;
#pragma unroll
    for (int k = 0; k < 4; k++) {
        int idx = base4 + k;
        if (idx < nb) {
            int c = bins[idx];
            dinv[lo + idx] = rsqrtf((float)c + 1.0f);
            ex[k] = run;
            run += c;
        }
    }
    tsum[tid] = run;
    __syncthreads();
    for (int off = 1; off < 256; off <<= 1) {
        int u = (tid >= off) ? tsum[tid - off] : 0;
        __syncthreads();
        tsum[tid] += u;
        __syncthreads();
    }
    const int toff = ((tid > 0) ? tsum[tid - 1] : 0) + vbase[b];
    __syncthreads();   // everyone done reading tsum before bins overwritten? bins!=tsum, safe; keep for clarity
#pragma unroll
    for (int k = 0; k < 4; k++) {
        int idx = base4 + k;
        if (idx < nb) {
            int st = toff + ex[k];
            bins[idx] = st;           // running fill cursor (absolute index into srcids)
            rowptr[lo + idx] = st;
        }
    }
    __syncthreads();
    for (int i = tid; i < cnt; i += 256) {
        int2 p = mine[i];
        int pos = atomicAdd(&bins[p.y - lo], 1);
        srcids[pos] = p.x;
    }
}

// ---------------- weight transpose+convert (both layers in one kernel) ----------------
__global__ void conv_w2(const float* __restrict__ W1, u16* __restrict__ B1, int K1, int N1,
                        const float* __restrict__ W2, u16* __restrict__ B2, int K2, int N2) {
    int i = blockIdx.x * 256 + threadIdx.x;
    int sz1 = K1 * N1;
    if (i < sz1) {
        int n = i / K1, k = i - n * K1;
        B1[i] = f2bf(W1[(size_t)k * N1 + n]);
    } else if (i - sz1 < K2 * N2) {
        int j = i - sz1;
        int n = j / K2, k = j - n * K2;
        B2[j] = f2bf(W2[(size_t)k * N2 + n]);
    }
}

// ---------------- MFMA bf16 GEMM: G[m][n] = bf16( (A @ Bt^T)[m][n] * dinv[m] ) ----------------
template <int K, int BN, int IFR, int JFR, int WM, int WN, bool ABF16>
__launch_bounds__(256)
__global__ void gemm_mfma(const void* __restrict__ Av, const u16* __restrict__ Bt,
                          const float* __restrict__ dinv, u16* __restrict__ G, int M) {
    constexpr int BM = 128, BK = 32;
    __shared__ u16 As[BM][BK];   // 64 B rows -> conflict-free b128 frag reads
    __shared__ u16 Bs[BN][BK];
    const int tid = threadIdx.x;
    const int lane = tid & 63, wave = tid >> 6;
    const int r = lane & 15, g = lane >> 4;
    const int wm = wave % WM, wn = wave / WM;
    const int m0 = blockIdx.x * BM;

    f32x4 acc[IFR][JFR];
#pragma unroll
    for (int i = 0; i < IFR; i++)
#pragma unroll
        for (int j = 0; j < JFR; j++) acc[i][j] = (f32x4){0.f, 0.f, 0.f, 0.f};

    for (int k0 = 0; k0 < K; k0 += BK) {
#pragma unroll
        for (int p = 0; p < 4; p++) {
            int q = tid + p * 256;
            int row = q >> 3, kq = (q & 7) << 2;
            int gr = m0 + row; if (gr >= M) gr = M - 1;   // clamp; stores guarded
            if constexpr (ABF16) {
                const u16* A = (const u16*)Av;
                *(u16x4*)&As[row][kq] = *(const u16x4*)(A + (size_t)gr * K + k0 + kq);
            } else {
                const float* A = (const float*)Av;
                float4 a = *(const float4*)(A + (size_t)gr * K + k0 + kq);
                u16x4 v = { f2bf(a.x), f2bf(a.y), f2bf(a.z), f2bf(a.w) };
                *(u16x4*)&As[row][kq] = v;
            }
        }
#pragma unroll
        for (int p = 0; p < BN / 32; p++) {
            int q = tid + p * 256;
            int row = q >> 3, kq = (q & 7) << 2;
            *(u16x4*)&Bs[row][kq] = *(const u16x4*)(Bt + (size_t)row * K + k0 + kq);
        }
        __syncthreads();

        bf16x8 af[IFR], bfr[JFR];
#pragma unroll
        for (int i = 0; i < IFR; i++)
            af[i] = *(const bf16x8*)&As[wm * (IFR * 16) + i * 16 + r][g * 8];
#pragma unroll
        for (int j = 0; j < JFR; j++)
            bfr[j] = *(const bf16x8*)&Bs[wn * (JFR * 16) + j * 16 + r][g * 8];
#pragma unroll
        for (int i = 0; i < IFR; i++)
#pragma unroll
            for (int j = 0; j < JFR; j++)
                acc[i][j] = __builtin_amdgcn_mfma_f32_16x16x32_bf16(af[i], bfr[j], acc[i][j], 0, 0, 0);
        __syncthreads();
    }

    // C/D layout: col=lane&15, row=(lane>>4)*4+reg
#pragma unroll
    for (int i = 0; i < IFR; i++) {
#pragma unroll
        for (int t = 0; t < 4; t++) {
            int row = m0 + wm * (IFR * 16) + i * 16 + g * 4 + t;
            if (row < M) {
                float dn = dinv[row];
#pragma unroll
                for (int j = 0; j < JFR; j++) {
                    int col = wn * (JFR * 16) + j * 16 + r;
                    G[(size_t)row * BN + col] = f2bf(acc[i][j][t] * dn);
                }
            }
        }
    }
}

// ---------------- agg, F=128: 2 edges/wave (32-lane halves, 8B loads), 16 gathers/wave in flight ----------------
__launch_bounds__(256)
__global__ void agg128(const uint2* __restrict__ g1, const float4* __restrict__ bias,
                       const int* __restrict__ rowptr, const int* __restrict__ srcids,
                       const float* __restrict__ dinv, uint2* __restrict__ h1, int n) {
    const int wv = threadIdx.x >> 6, lane = threadIdx.x & 63;
    const int node = blockIdx.x * 4 + wv;
    if (node >= n) return;
    const int h = lane >> 5, c = lane & 31;
    const float dn = dinv[node];
    float a0 = 0.f, a1 = 0.f, a2 = 0.f, a3 = 0.f;
    if (h == 0) {
        uint2 sv = g1[(size_t)node * 32 + c];
        a0 = bf_lo(sv.x); a1 = bf_hi(sv.x); a2 = bf_lo(sv.y); a3 = bf_hi(sv.y);
    }
    const int end = rowptr[node + 1];
    int j = rowptr[node] + h;
    for (; j + 14 < end; j += 16) {     // 8 gathers/half-wave in flight = 16 edges/wave
        int s0 = srcids[j],      s1 = srcids[j + 2],  s2 = srcids[j + 4],  s3 = srcids[j + 6];
        int s4 = srcids[j + 8],  s5 = srcids[j + 10], s6 = srcids[j + 12], s7 = srcids[j + 14];
        uint2 v0 = g1[(size_t)s0 * 32 + c];
        uint2 v1 = g1[(size_t)s1 * 32 + c];
        uint2 v2 = g1[(size_t)s2 * 32 + c];
        uint2 v3 = g1[(size_t)s3 * 32 + c];
        uint2 v4 = g1[(size_t)s4 * 32 + c];
        uint2 v5 = g1[(size_t)s5 * 32 + c];
        uint2 v6 = g1[(size_t)s6 * 32 + c];
        uint2 v7 = g1[(size_t)s7 * 32 + c];
        a0 += ((bf_lo(v0.x) + bf_lo(v1.x)) + (bf_lo(v2.x) + bf_lo(v3.x)))
            + ((bf_lo(v4.x) + bf_lo(v5.x)) + (bf_lo(v6.x) + bf_lo(v7.x)));
        a1 += ((bf_hi(v0.x) + bf_hi(v1.x)) + (bf_hi(v2.x) + bf_hi(v3.x)))
            + ((bf_hi(v4.x) + bf_hi(v5.x)) + (bf_hi(v6.x) + bf_hi(v7.x)));
        a2 += ((bf_lo(v0.y) + bf_lo(v1.y)) + (bf_lo(v2.y) + bf_lo(v3.y)))
            + ((bf_lo(v4.y) + bf_lo(v5.y)) + (bf_lo(v6.y) + bf_lo(v7.y)));
        a3 += ((bf_hi(v0.y) + bf_hi(v1.y)) + (bf_hi(v2.y) + bf_hi(v3.y)))
            + ((bf_hi(v4.y) + bf_hi(v5.y)) + (bf_hi(v6.y) + bf_hi(v7.y)));
    }
    for (; j < end; j += 2) {
        uint2 v = g1[(size_t)srcids[j] * 32 + c];
        a0 += bf_lo(v.x); a1 += bf_hi(v.x); a2 += bf_lo(v.y); a3 += bf_hi(v.y);
    }
    a0 += __shfl_xor(a0, 32); a1 += __shfl_xor(a1, 32);
    a2 += __shfl_xor(a2, 32); a3 += __shfl_xor(a3, 32);
    if (h == 0) {
        float4 bb = bias[c];
        float r0 = fmaxf(a0 * dn + bb.x, 0.f);
        float r1 = fmaxf(a1 * dn + bb.y, 0.f);
        float r2 = fmaxf(a2 * dn + bb.z, 0.f);
        float r3 = fmaxf(a3 * dn + bb.w, 0.f);
        uint2 w;
        w.x = (u32)f2bf(r0) | ((u32)f2bf(r1) << 16);
        w.y = (u32)f2bf(r2) | ((u32)f2bf(r3) << 16);
        h1[(size_t)node * 32 + c] = w;
    }
}

// ---------------- agg, F=64: 2 edges/wave (32-lane halves, 4B loads), 16 gathers/wave in flight ----------------
__launch_bounds__(256)
__global__ void agg64(const u32* __restrict__ g2, const float2* __restrict__ bias,
                      const int* __restrict__ rowptr, const int* __restrict__ srcids,
                      const float* __restrict__ dinv, float* __restrict__ h2, int n) {
    const int wv = threadIdx.x >> 6, lane = threadIdx.x & 63;
    const int node = blockIdx.x * 4 + wv;
    if (node >= n) return;
    const int h = lane >> 5, c = lane & 31;
    const float dn = dinv[node];
    float a0 = 0.f, a1 = 0.f;
    if (h == 0) {
        u32 sv = g2[(size_t)node * 32 + c];
        a0 = bf_lo(sv); a1 = bf_hi(sv);
    }
    const int end = rowptr[node + 1];
    int j = rowptr[node] + h;
    for (; j + 14 < end; j += 16) {     // 8 gathers/half-wave in flight = 16 edges/wave
        int s0 = srcids[j],      s1 = srcids[j + 2],  s2 = srcids[j + 4],  s3 = srcids[j + 6];
        int s4 = srcids[j + 8],  s5 = srcids[j + 10], s6 = srcids[j + 12], s7 = srcids[j + 14];
        u32 v0 = g2[(size_t)s0 * 32 + c];
        u32 v1 = g2[(size_t)s1 * 32 + c];
        u32 v2 = g2[(size_t)s2 * 32 + c];
        u32 v3 = g2[(size_t)s3 * 32 + c];
        u32 v4 = g2[(size_t)s4 * 32 + c];
        u32 v5 = g2[(size_t)s5 * 32 + c];
        u32 v6 = g2[(size_t)s6 * 32 + c];
        u32 v7 = g2[(size_t)s7 * 32 + c];
        a0 += ((bf_lo(v0) + bf_lo(v1)) + (bf_lo(v2) + bf_lo(v3)))
            + ((bf_lo(v4) + bf_lo(v5)) + (bf_lo(v6) + bf_lo(v7)));
        a1 += ((bf_hi(v0) + bf_hi(v1)) + (bf_hi(v2) + bf_hi(v3)))
            + ((bf_hi(v4) + bf_hi(v5)) + (bf_hi(v6) + bf_hi(v7)));
    }
    for (; j < end; j += 2) {
        u32 v = g2[(size_t)srcids[j] * 32 + c];
        a0 += bf_lo(v); a1 += bf_hi(v);
    }
    a0 += __shfl_xor(a0, 32);
    a1 += __shfl_xor(a1, 32);
    if (h == 0) {
        float2 bb = bias[c];
        float2 w;
        w.x = a0 * dn + bb.x;
        w.y = a1 * dn + bb.y;
        *(float2*)&h2[(size_t)node * 64 + c * 2] = w;
    }
}

// ---------------- final: out = log_softmax(h2 @ Wo + bo) ----------------
__launch_bounds__(256)
__global__ void out_kernel(const float* __restrict__ h2, const float* __restrict__ Wo,
                           const float* __restrict__ bo, float* __restrict__ out, int n) {
    __shared__ float Ws[64 * 40];
    __shared__ float bs[40];
    for (int i = threadIdx.x; i < 64 * 40; i += 256) Ws[i] = Wo[i];
    if (threadIdx.x < 40) bs[threadIdx.x] = bo[threadIdx.x];
    __syncthreads();

    int row = blockIdx.x * 256 + threadIdx.x;
    if (row >= n) return;

    float acc[40];
#pragma unroll
    for (int j = 0; j < 40; j++) acc[j] = 0.f;

    const float4* hr = (const float4*)(h2 + (size_t)row * 64);
#pragma unroll 4
    for (int k4 = 0; k4 < 16; k4++) {
        float4 h4 = hr[k4];
        float hv[4] = {h4.x, h4.y, h4.z, h4.w};
#pragma unroll
        for (int u = 0; u < 4; u++) {
            float a = hv[u];
            const float* wrow = &Ws[(k4 * 4 + u) * 40];
#pragma unroll
            for (int j = 0; j < 40; j++) acc[j] += a * wrow[j];
        }
    }

    float m = -1e30f;
#pragma unroll
    for (int j = 0; j < 40; j++) { acc[j] += bs[j]; m = fmaxf(m, acc[j]); }
    float s = 0.f;
#pragma unroll
    for (int j = 0; j < 40; j++) s += expf(acc[j] - m);
    float lse = m + logf(s);

    float* op = out + (size_t)row * 40;
#pragma unroll
    for (int j4 = 0; j4 < 10; j4++) {
        float4 w = { acc[j4 * 4] - lse, acc[j4 * 4 + 1] - lse,
                     acc[j4 * 4 + 2] - lse, acc[j4 * 4 + 3] - lse };
        *(float4*)(op + j4 * 4) = w;
    }
}

extern "C" void kernel_launch(void* const* d_in, const int* in_sizes, int n_in,
                              void* d_out, int out_size, void* d_ws, size_t ws_size,
                              hipStream_t stream) {
    const float* x  = (const float*)d_in[0];
    const int*   ei = (const int*)d_in[1];
    const float* W1 = (const float*)d_in[2];
    const float* b1 = (const float*)d_in[3];
    const float* W2 = (const float*)d_in[4];
    const float* b2 = (const float*)d_in[5];
    const float* Wo = (const float*)d_in[6];
    const float* bo = (const float*)d_in[7];
    float* out = (float*)d_out;

    const int HID  = in_sizes[3];           // 128
    const int IN   = in_sizes[2] / HID;     // 256
    const int HID1 = in_sizes[5];           // 64
    const int N = in_sizes[0] / IN;         // 100000
    const int E = in_sizes[1] / 2;          // 1600000
    const int* src = ei;
    const int* dst = ei + E;

    const int R1 = (N + NB1 - 1) / NB1;     // 6250
    const int R2 = (N + NB2 - 1) / NB2;     // 782
    const int bcap1 = E / NB1 + 8192;       // 108192 (+26 sigma)
    const int bcap2 = E / NB2 + 3884;       // 16384  (+35 sigma)

    char* ws = (char*)d_ws;
    size_t off = 0;
    auto alloc = [&](size_t bytes) -> void* {
        void* p = ws + off;
        off += (bytes + 255) / 256 * 256;
        return p;
    };
    float* dinv   = (float*)alloc((size_t)N * 4);
    int*   rowptr = (int*)alloc((size_t)(N + 1) * 4);
    int*   atom   = (int*)alloc((NB1 + NB2) * 4);          // bcur1 | bcur2 (one memset)
    int*   bcur1  = atom;
    int*   bcur2  = atom + NB1;
    int*   vbase  = (int*)alloc(NB2 * 4);
    int*   srcids = (int*)alloc((size_t)E * 4);
    u16*   W1t    = (u16*)alloc((size_t)IN * HID * 2);     // [128][256] bf16
    u16*   W2t    = (u16*)alloc((size_t)HID * HID1 * 2);   // [64][128] bf16
    // shared region: bp1+bp2 (CSR build) -> g1 (gemm1/agg128) -> h2 (agg64/out); strictly sequential
    size_t bp1Bytes = (size_t)NB1 * bcap1 * 8;
    size_t bp2Bytes = (size_t)NB2 * bcap2 * 8;
    size_t sharedBytes = bp1Bytes + bp2Bytes;              // ~30.6 MB
    size_t gBytes = (size_t)N * HID * 2;                   // 25.6 MB (g1); h2 = N*64*4 same size
    if (gBytes > sharedBytes) sharedBytes = gBytes;
    char*  shared = (char*)alloc(sharedBytes);
    int2*  bp1    = (int2*)shared;
    int2*  bp2    = (int2*)(shared + bp1Bytes);
    u16*   g1     = (u16*)shared;
    float* h2     = (float*)shared;
    u16*   h1     = (u16*)alloc((size_t)N * HID * 2);      // bf16 [N][128]
    u16*   g2     = (u16*)alloc((size_t)N * HID1 * 2);     // bf16 [N][64]

    // ---- CSR build: zero per-edge global atomics ----
    hipMemsetAsync(atom, 0, (NB1 + NB2) * 4, stream);
    route1<<<512, 256, 0, stream>>>(src, dst, E, R1, bcur1, bp1, bcap1);
    int r2grid = NB1 * ((bcap1 + 255) / 256);
    route2<<<r2grid, 256, 0, stream>>>(bp1, bcur1, bcap1, R1, R2, bcur2, bp2, bcap2);
    scan_vcnt<<<1, NB2, 0, stream>>>(bcur2, vbase, rowptr, N, E);
    build_csr<<<NB2, 256, 0, stream>>>(bp2, bcur2, bcap2, vbase, R2, N, rowptr, dinv, srcids);

    // weights -> bf16 transposed (both in one launch)
    conv_w2<<<(IN * HID + HID * HID1 + 255) / 256, 256, 0, stream>>>(
        W1, W1t, IN, HID, W2, W2t, HID, HID1);

    const int gblocks = (N + 127) / 128;
    // layer 1: g1 = bf16((x @ W1) * dinv); h1 = bf16(relu(agg(g1)*dinv + b1))
    gemm_mfma<256, 128, 4, 4, 2, 2, false><<<gblocks, 256, 0, stream>>>(x, W1t, dinv, g1, N);
    agg128<<<(N + 3) / 4, 256, 0, stream>>>((const uint2*)g1, (const float4*)b1,
                                            rowptr, srcids, dinv, (uint2*)h1, N);

    // layer 2: g2 = bf16((h1 @ W2) * dinv); h2 = agg(g2)*dinv + b2 (fp32)
    gemm_mfma<128, 64, 2, 4, 4, 1, true><<<gblocks, 256, 0, stream>>>(h1, W2t, dinv, g2, N);
    agg64<<<(N + 3) / 4, 256, 0, stream>>>((const u32*)g2, (const float2*)b2,
                                           rowptr, srcids, dinv, h2, N);

    // output head + log_softmax
    out_kernel<<<(N + 255) / 256, 256, 0, stream>>>(h2, Wo, bo, out, N);
    (void)ws_size; (void)n_in; (void)out_size; (void)HID1;
}

// Round 7
// 289.337 us; speedup vs baseline: 1.5384x; 1.2510x over previous
//
#include <hip/hip_runtime.h>
#include <hip/hip_bf16.h>

typedef unsigned short u16;
typedef unsigned int u32;
typedef __attribute__((ext_vector_type(8))) short bf16x8;   // 8 bf16 (4 VGPRs)
typedef __attribute__((ext_vector_type(4))) float f32x4;
typedef __attribute__((ext_vector_type(4))) u16 u16x4;

__device__ __forceinline__ u16 f2bf(float f) {
    union { float f; u32 u; } v; v.f = f;
    u32 r = v.u + 0x7FFF + ((v.u >> 16) & 1);   // RNE
    return (u16)(r >> 16);
}
__device__ __forceinline__ float bf_lo(u32 u) {
    union { u32 u; float f; } v; v.u = u << 16; return v.f;
}
__device__ __forceinline__ float bf_hi(u32 u) {
    union { u32 u; float f; } v; v.u = u & 0xFFFF0000u; return v.f;
}
__device__ __forceinline__ u32 pack2(float a, float b) {
    return (u32)f2bf(a) | ((u32)f2bf(b) << 16);
}

#define NB1 16     // super-buckets (stage 1)
#define NB2 256    // final buckets

// ---------------- stage 1: edges -> 16 dst-range super-buckets ----------------
__launch_bounds__(256)
__global__ void route1(const int* __restrict__ src, const int* __restrict__ dst, int E, int R1,
                       int* __restrict__ bcur, int2* __restrict__ bp, int bcap) {
    __shared__ int lcnt[NB1], lbase[NB1];
    const int tid = threadIdx.x;
    const int ntile = (E + 255) >> 8;
    for (int t = blockIdx.x; t < ntile; t += gridDim.x) {
        if (tid < NB1) lcnt[tid] = 0;
        __syncthreads();
        int e = (t << 8) + tid;
        bool act = (e < E);
        int s = 0, d = 0, b = 0, pos = 0;
        if (act) {
            d = dst[e]; s = src[e];
            b = d / R1;
            pos = atomicAdd(&lcnt[b], 1);
        }
        __syncthreads();
        if (tid < NB1 && lcnt[tid]) lbase[tid] = atomicAdd(&bcur[tid], lcnt[tid]);
        __syncthreads();
        if (act) {
            int idx = lbase[b] + pos;
            if (idx < bcap) bp[(size_t)b * bcap + idx] = (int2){s, d};
        }
    }
}

// ---------------- stage 2: super-bucket -> 16 final buckets each (256 total) ----------------
__launch_bounds__(256)
__global__ void route2(const int2* __restrict__ bp1, const int* __restrict__ bcnt1, int bcap1,
                       int R1, int R2, int* __restrict__ bcur2, int2* __restrict__ bp2, int bcap2) {
    __shared__ int lcnt[32], lbase[32];
    const int sb = blockIdx.x & (NB1 - 1);
    const int t = blockIdx.x >> 4;
    const int tid = threadIdx.x;
    int cnt = bcnt1[sb];
    if (cnt > bcap1) cnt = bcap1;
    if (t * 256 >= cnt) return;
    if (tid < 32) lcnt[tid] = 0;
    __syncthreads();
    const int i = t * 256 + tid;
    const int f0 = (sb * R1) / R2;
    bool act = (i < cnt);
    int2 p; int rel = 0, pos = 0;
    if (act) {
        p = bp1[(size_t)sb * bcap1 + i];
        rel = p.y / R2 - f0;                  // span <= 17 < 32
        pos = atomicAdd(&lcnt[rel], 1);
    }
    __syncthreads();
    if (tid < 32 && lcnt[tid]) lbase[tid] = atomicAdd(&bcur2[f0 + tid], lcnt[tid]);
    __syncthreads();
    if (act) {
        int idx = lbase[rel] + pos;
        if (idx < bcap2) bp2[(size_t)(f0 + rel) * bcap2 + idx] = p;
    }
}

// ---------------- exclusive scan of 256 bucket counts -> global srcids bases ----------------
__global__ void scan_vcnt(const int* __restrict__ bcnt2, int* __restrict__ vbase,
                          int* __restrict__ rowptr, int N, int E) {
    __shared__ int sd[NB2];
    const int t = threadIdx.x;
    int v = bcnt2[t];
    sd[t] = v;
    __syncthreads();
    for (int off = 1; off < NB2; off <<= 1) {
        int u = (t >= off) ? sd[t - off] : 0;
        __syncthreads();
        sd[t] += u;
        __syncthreads();
    }
    vbase[t] = sd[t] - v;   // exclusive
    if (t == NB2 - 1) rowptr[N] = E;
}

// ---------------- per-bucket CSR build: LDS histogram + scan + LDS-atomic fill ----------------
__launch_bounds__(256)
__global__ void build_csr(const int2* __restrict__ bp2, const int* __restrict__ bcnt2, int bcap2,
                          const int* __restrict__ vbase, int R2, int N,
                          int* __restrict__ rowptr, float* __restrict__ dinv,
                          int* __restrict__ srcids) {
    __shared__ int bins[1024];       // R2 <= 1024
    __shared__ int tsum[256];
    const int b = blockIdx.x;
    const int tid = threadIdx.x;
    const int lo = b * R2;
    int hi = lo + R2; if (hi > N) hi = N;
    const int nb = hi - lo;
    if (nb <= 0) return;
    int cnt = bcnt2[b];
    if (cnt > bcap2) cnt = bcap2;
    const int2* mine = bp2 + (size_t)b * bcap2;

    for (int i = tid; i < nb; i += 256) bins[i] = 0;
    __syncthreads();
    for (int i = tid; i < cnt; i += 256) {
        int2 p = mine[i];
        atomicAdd(&bins[p.y - lo], 1);
    }
    __syncthreads();

    const int base4 = tid * 4;
    int ex[4]; int run = 0;
#pragma unroll
    for (int k = 0; k < 4; k++) {
        int idx = base4 + k;
        if (idx < nb) {
            int c = bins[idx];
            dinv[lo + idx] = rsqrtf((float)c + 1.0f);
            ex[k] = run;
            run += c;
        }
    }
    tsum[tid] = run;
    __syncthreads();
    for (int off = 1; off < 256; off <<= 1) {
        int u = (tid >= off) ? tsum[tid - off] : 0;
        __syncthreads();
        tsum[tid] += u;
        __syncthreads();
    }
    const int toff = ((tid > 0) ? tsum[tid - 1] : 0) + vbase[b];
    __syncthreads();
#pragma unroll
    for (int k = 0; k < 4; k++) {
        int idx = base4 + k;
        if (idx < nb) {
            int st = toff + ex[k];
            bins[idx] = st;           // absolute fill cursor into srcids
            rowptr[lo + idx] = st;
        }
    }
    __syncthreads();
    for (int i = tid; i < cnt; i += 256) {
        int2 p = mine[i];
        int pos = atomicAdd(&bins[p.y - lo], 1);
        srcids[pos] = p.x;
    }
}

// ---------------- weight transpose+convert (both layers in one kernel) ----------------
__global__ void conv_w2(const float* __restrict__ W1, u16* __restrict__ B1, int K1, int N1,
                        const float* __restrict__ W2, u16* __restrict__ B2, int K2, int N2) {
    int i = blockIdx.x * 256 + threadIdx.x;
    int sz1 = K1 * N1;
    if (i < sz1) {
        int n = i / K1, k = i - n * K1;
        B1[i] = f2bf(W1[(size_t)k * N1 + n]);
    } else if (i - sz1 < K2 * N2) {
        int j = i - sz1;
        int n = j / K2, k = j - n * K2;
        B2[j] = f2bf(W2[(size_t)k * N2 + n]);
    }
}

// ---------------- MFMA bf16 GEMM: G[m][n] = bf16( (A @ Bt^T)[m][n] * dinv[m] ) ----------------
template <int K, int BN, int IFR, int JFR, int WM, int WN, bool ABF16>
__launch_bounds__(256)
__global__ void gemm_mfma(const void* __restrict__ Av, const u16* __restrict__ Bt,
                          const float* __restrict__ dinv, u16* __restrict__ G, int M) {
    constexpr int BM = 128, BK = 32;
    __shared__ u16 As[BM][BK];   // 64 B rows -> conflict-free b128 frag reads
    __shared__ u16 Bs[BN][BK];
    const int tid = threadIdx.x;
    const int lane = tid & 63, wave = tid >> 6;
    const int r = lane & 15, g = lane >> 4;
    const int wm = wave % WM, wn = wave / WM;
    const int m0 = blockIdx.x * BM;

    f32x4 acc[IFR][JFR];
#pragma unroll
    for (int i = 0; i < IFR; i++)
#pragma unroll
        for (int j = 0; j < JFR; j++) acc[i][j] = (f32x4){0.f, 0.f, 0.f, 0.f};

    for (int k0 = 0; k0 < K; k0 += BK) {
#pragma unroll
        for (int p = 0; p < 4; p++) {
            int q = tid + p * 256;
            int row = q >> 3, kq = (q & 7) << 2;
            int gr = m0 + row; if (gr >= M) gr = M - 1;   // clamp; stores guarded
            if constexpr (ABF16) {
                const u16* A = (const u16*)Av;
                *(u16x4*)&As[row][kq] = *(const u16x4*)(A + (size_t)gr * K + k0 + kq);
            } else {
                const float* A = (const float*)Av;
                float4 a = *(const float4*)(A + (size_t)gr * K + k0 + kq);
                u16x4 v = { f2bf(a.x), f2bf(a.y), f2bf(a.z), f2bf(a.w) };
                *(u16x4*)&As[row][kq] = v;
            }
        }
#pragma unroll
        for (int p = 0; p < BN / 32; p++) {
            int q = tid + p * 256;
            int row = q >> 3, kq = (q & 7) << 2;
            *(u16x4*)&Bs[row][kq] = *(const u16x4*)(Bt + (size_t)row * K + k0 + kq);
        }
        __syncthreads();

        bf16x8 af[IFR], bfr[JFR];
#pragma unroll
        for (int i = 0; i < IFR; i++)
            af[i] = *(const bf16x8*)&As[wm * (IFR * 16) + i * 16 + r][g * 8];
#pragma unroll
        for (int j = 0; j < JFR; j++)
            bfr[j] = *(const bf16x8*)&Bs[wn * (JFR * 16) + j * 16 + r][g * 8];
#pragma unroll
        for (int i = 0; i < IFR; i++)
#pragma unroll
            for (int j = 0; j < JFR; j++)
                acc[i][j] = __builtin_amdgcn_mfma_f32_16x16x32_bf16(af[i], bfr[j], acc[i][j], 0, 0, 0);
        __syncthreads();
    }

    // C/D layout: col=lane&15, row=(lane>>4)*4+reg
#pragma unroll
    for (int i = 0; i < IFR; i++) {
#pragma unroll
        for (int t = 0; t < 4; t++) {
            int row = m0 + wm * (IFR * 16) + i * 16 + g * 4 + t;
            if (row < M) {
                float dn = dinv[row];
#pragma unroll
                for (int j = 0; j < JFR; j++) {
                    int col = wn * (JFR * 16) + j * 16 + r;
                    G[(size_t)row * BN + col] = f2bf(acc[i][j][t] * dn);
                }
            }
        }
    }
}

// ---------------- agg F=128: one 16-lane quarter per node; lane owns 16B slice ----------------
// unroll-4 engages at degree>=4 (~100% of edges); no cross-lane reduction at all
__launch_bounds__(256)
__global__ void agg128(const uint4* __restrict__ g1, const float4* __restrict__ bias,
                       const int* __restrict__ rowptr, const int* __restrict__ srcids,
                       const float* __restrict__ dinv, uint4* __restrict__ h1, int n) {
    const int tq = threadIdx.x >> 4;       // quarter within block [0,16)
    const int c  = threadIdx.x & 15;       // 16B slice index
    const int node = blockIdx.x * 16 + tq;
    if (node >= n) return;
    const float dn = dinv[node];
    uint4 sv = g1[(size_t)node * 16 + c];  // self
    float a0 = bf_lo(sv.x), a1 = bf_hi(sv.x), a2 = bf_lo(sv.y), a3 = bf_hi(sv.y);
    float a4 = bf_lo(sv.z), a5 = bf_hi(sv.z), a6 = bf_lo(sv.w), a7 = bf_hi(sv.w);
    const int end = rowptr[node + 1];
    int j = rowptr[node];
    for (; j + 3 < end; j += 4) {          // 4 gathers in flight per quarter
        int s0 = srcids[j], s1 = srcids[j + 1], s2 = srcids[j + 2], s3 = srcids[j + 3];
        uint4 v0 = g1[(size_t)s0 * 16 + c];
        uint4 v1 = g1[(size_t)s1 * 16 + c];
        uint4 v2 = g1[(size_t)s2 * 16 + c];
        uint4 v3 = g1[(size_t)s3 * 16 + c];
        a0 += (bf_lo(v0.x) + bf_lo(v1.x)) + (bf_lo(v2.x) + bf_lo(v3.x));
        a1 += (bf_hi(v0.x) + bf_hi(v1.x)) + (bf_hi(v2.x) + bf_hi(v3.x));
        a2 += (bf_lo(v0.y) + bf_lo(v1.y)) + (bf_lo(v2.y) + bf_lo(v3.y));
        a3 += (bf_hi(v0.y) + bf_hi(v1.y)) + (bf_hi(v2.y) + bf_hi(v3.y));
        a4 += (bf_lo(v0.z) + bf_lo(v1.z)) + (bf_lo(v2.z) + bf_lo(v3.z));
        a5 += (bf_hi(v0.z) + bf_hi(v1.z)) + (bf_hi(v2.z) + bf_hi(v3.z));
        a6 += (bf_lo(v0.w) + bf_lo(v1.w)) + (bf_lo(v2.w) + bf_lo(v3.w));
        a7 += (bf_hi(v0.w) + bf_hi(v1.w)) + (bf_hi(v2.w) + bf_hi(v3.w));
    }
    for (; j < end; j++) {
        uint4 v = g1[(size_t)srcids[j] * 16 + c];
        a0 += bf_lo(v.x); a1 += bf_hi(v.x); a2 += bf_lo(v.y); a3 += bf_hi(v.y);
        a4 += bf_lo(v.z); a5 += bf_hi(v.z); a6 += bf_lo(v.w); a7 += bf_hi(v.w);
    }
    float4 b0 = bias[c * 2], b1v = bias[c * 2 + 1];
    uint4 w;
    w.x = pack2(fmaxf(a0 * dn + b0.x, 0.f), fmaxf(a1 * dn + b0.y, 0.f));
    w.y = pack2(fmaxf(a2 * dn + b0.z, 0.f), fmaxf(a3 * dn + b0.w, 0.f));
    w.z = pack2(fmaxf(a4 * dn + b1v.x, 0.f), fmaxf(a5 * dn + b1v.y, 0.f));
    w.w = pack2(fmaxf(a6 * dn + b1v.z, 0.f), fmaxf(a7 * dn + b1v.w, 0.f));
    h1[(size_t)node * 16 + c] = w;
}

// ---------------- agg F=64: one 16-lane quarter per node; lane owns 8B slice; bf16 out ----------------
__launch_bounds__(256)
__global__ void agg64(const uint2* __restrict__ g2, const float4* __restrict__ bias,
                      const int* __restrict__ rowptr, const int* __restrict__ srcids,
                      const float* __restrict__ dinv, uint2* __restrict__ h2, int n) {
    const int tq = threadIdx.x >> 4;
    const int c  = threadIdx.x & 15;
    const int node = blockIdx.x * 16 + tq;
    if (node >= n) return;
    const float dn = dinv[node];
    uint2 sv = g2[(size_t)node * 16 + c];
    float a0 = bf_lo(sv.x), a1 = bf_hi(sv.x), a2 = bf_lo(sv.y), a3 = bf_hi(sv.y);
    const int end = rowptr[node + 1];
    int j = rowptr[node];
    for (; j + 3 < end; j += 4) {
        int s0 = srcids[j], s1 = srcids[j + 1], s2 = srcids[j + 2], s3 = srcids[j + 3];
        uint2 v0 = g2[(size_t)s0 * 16 + c];
        uint2 v1 = g2[(size_t)s1 * 16 + c];
        uint2 v2 = g2[(size_t)s2 * 16 + c];
        uint2 v3 = g2[(size_t)s3 * 16 + c];
        a0 += (bf_lo(v0.x) + bf_lo(v1.x)) + (bf_lo(v2.x) + bf_lo(v3.x));
        a1 += (bf_hi(v0.x) + bf_hi(v1.x)) + (bf_hi(v2.x) + bf_hi(v3.x));
        a2 += (bf_lo(v0.y) + bf_lo(v1.y)) + (bf_lo(v2.y) + bf_lo(v3.y));
        a3 += (bf_hi(v0.y) + bf_hi(v1.y)) + (bf_hi(v2.y) + bf_hi(v3.y));
    }
    for (; j < end; j++) {
        uint2 v = g2[(size_t)srcids[j] * 16 + c];
        a0 += bf_lo(v.x); a1 += bf_hi(v.x); a2 += bf_lo(v.y); a3 += bf_hi(v.y);
    }
    float4 bb = bias[c];
    uint2 w;
    w.x = pack2(a0 * dn + bb.x, a1 * dn + bb.y);
    w.y = pack2(a2 * dn + bb.z, a3 * dn + bb.w);
    h2[(size_t)node * 16 + c] = w;
}

// ---------------- final: out = log_softmax(h2 @ Wo + bo), h2 bf16 ----------------
__launch_bounds__(256)
__global__ void out_kernel(const uint4* __restrict__ h2, const float* __restrict__ Wo,
                           const float* __restrict__ bo, float* __restrict__ out, int n) {
    __shared__ float Ws[64 * 40];
    __shared__ float bs[40];
    for (int i = threadIdx.x; i < 64 * 40; i += 256) Ws[i] = Wo[i];
    if (threadIdx.x < 40) bs[threadIdx.x] = bo[threadIdx.x];
    __syncthreads();

    int row = blockIdx.x * 256 + threadIdx.x;
    if (row >= n) return;

    float acc[40];
#pragma unroll
    for (int j = 0; j < 40; j++) acc[j] = 0.f;

    const uint4* hr = h2 + (size_t)row * 8;   // 64 bf16 = 8 x uint4
#pragma unroll 2
    for (int k8 = 0; k8 < 8; k8++) {
        uint4 v = hr[k8];
        float hv[8] = { bf_lo(v.x), bf_hi(v.x), bf_lo(v.y), bf_hi(v.y),
                        bf_lo(v.z), bf_hi(v.z), bf_lo(v.w), bf_hi(v.w) };
#pragma unroll
        for (int u = 0; u < 8; u++) {
            float a = hv[u];
            const float* wrow = &Ws[(k8 * 8 + u) * 40];
#pragma unroll
            for (int j = 0; j < 40; j++) acc[j] += a * wrow[j];
        }
    }

    float m = -1e30f;
#pragma unroll
    for (int j = 0; j < 40; j++) { acc[j] += bs[j]; m = fmaxf(m, acc[j]); }
    float s = 0.f;
#pragma unroll
    for (int j = 0; j < 40; j++) s += expf(acc[j] - m);
    float lse = m + logf(s);

    float* op = out + (size_t)row * 40;
#pragma unroll
    for (int j4 = 0; j4 < 10; j4++) {
        float4 w = { acc[j4 * 4] - lse, acc[j4 * 4 + 1] - lse,
                     acc[j4 * 4 + 2] - lse, acc[j4 * 4 + 3] - lse };
        *(float4*)(op + j4 * 4) = w;
    }
}

extern "C" void kernel_launch(void* const* d_in, const int* in_sizes, int n_in,
                              void* d_out, int out_size, void* d_ws, size_t ws_size,
                              hipStream_t stream) {
    const float* x  = (const float*)d_in[0];
    const int*   ei = (const int*)d_in[1];
    const float* W1 = (const float*)d_in[2];
    const float* b1 = (const float*)d_in[3];
    const float* W2 = (const float*)d_in[4];
    const float* b2 = (const float*)d_in[5];
    const float* Wo = (const float*)d_in[6];
    const float* bo = (const float*)d_in[7];
    float* out = (float*)d_out;

    const int HID  = in_sizes[3];           // 128
    const int IN   = in_sizes[2] / HID;     // 256
    const int HID1 = in_sizes[5];           // 64
    const int N = in_sizes[0] / IN;         // 100000
    const int E = in_sizes[1] / 2;          // 1600000
    const int* src = ei;
    const int* dst = ei + E;

    const int R1 = (N + NB1 - 1) / NB1;     // 6250
    const int R2 = (N + NB2 - 1) / NB2;     // 391
    const int bcap1 = E / NB1 + 8192;       // ~108K
    const int bcap2 = E / NB2 + 2048;       // ~8.3K (>20 sigma)

    char* ws = (char*)d_ws;
    size_t off = 0;
    auto alloc = [&](size_t bytes) -> void* {
        void* p = ws + off;
        off += (bytes + 255) / 256 * 256;
        return p;
    };
    float* dinv   = (float*)alloc((size_t)N * 4);
    int*   rowptr = (int*)alloc((size_t)(N + 1) * 4);
    int*   atom   = (int*)alloc((NB1 + NB2) * 4);          // bcur1 | bcur2 (one memset)
    int*   bcur1  = atom;
    int*   bcur2  = atom + NB1;
    int*   vbase  = (int*)alloc(NB2 * 4);
    int*   srcids = (int*)alloc((size_t)E * 4);
    u16*   W1t    = (u16*)alloc((size_t)IN * HID * 2);     // [128][256] bf16
    u16*   W2t    = (u16*)alloc((size_t)HID * HID1 * 2);   // [64][128] bf16
    // shared region: bp1+bp2 (CSR build) -> g1 (gemm1/agg128) -> h2 (agg64/out); sequential
    size_t bp1Bytes = (size_t)NB1 * bcap1 * 8;
    size_t bp2Bytes = (size_t)NB2 * bcap2 * 8;
    size_t sharedBytes = bp1Bytes + bp2Bytes;              // ~31 MB
    size_t gBytes = (size_t)N * HID * 2;                   // 25.6 MB
    if (gBytes > sharedBytes) sharedBytes = gBytes;
    char*  shared = (char*)alloc(sharedBytes);
    int2*  bp1    = (int2*)shared;
    int2*  bp2    = (int2*)(shared + bp1Bytes);
    u16*   g1     = (u16*)shared;
    u16*   h2     = (u16*)shared;                          // bf16 [N][64]
    u16*   h1     = (u16*)alloc((size_t)N * HID * 2);      // bf16 [N][128]
    u16*   g2     = (u16*)alloc((size_t)N * HID1 * 2);     // bf16 [N][64]

    // ---- CSR build: zero per-edge global atomics ----
    hipMemsetAsync(atom, 0, (NB1 + NB2) * 4, stream);
    route1<<<512, 256, 0, stream>>>(src, dst, E, R1, bcur1, bp1, bcap1);
    int r2grid = NB1 * ((bcap1 + 255) / 256);
    route2<<<r2grid, 256, 0, stream>>>(bp1, bcur1, bcap1, R1, R2, bcur2, bp2, bcap2);
    scan_vcnt<<<1, NB2, 0, stream>>>(bcur2, vbase, rowptr, N, E);
    build_csr<<<NB2, 256, 0, stream>>>(bp2, bcur2, bcap2, vbase, R2, N, rowptr, dinv, srcids);

    // weights -> bf16 transposed
    conv_w2<<<(IN * HID + HID * HID1 + 255) / 256, 256, 0, stream>>>(
        W1, W1t, IN, HID, W2, W2t, HID, HID1);

    const int gblocks = (N + 127) / 128;
    // layer 1: g1 = bf16((x @ W1) * dinv); h1 = bf16(relu(agg(g1)*dinv + b1))
    gemm_mfma<256, 128, 4, 4, 2, 2, false><<<gblocks, 256, 0, stream>>>(x, W1t, dinv, g1, N);
    agg128<<<(N + 15) / 16, 256, 0, stream>>>((const uint4*)g1, (const float4*)b1,
                                              rowptr, srcids, dinv, (uint4*)h1, N);

    // layer 2: g2 = bf16((h1 @ W2) * dinv); h2 = bf16(agg(g2)*dinv + b2)
    gemm_mfma<128, 64, 2, 4, 4, 1, true><<<gblocks, 256, 0, stream>>>(h1, W2t, dinv, g2, N);
    agg64<<<(N + 15) / 16, 256, 0, stream>>>((const uint2*)g2, (const float4*)b2,
                                             rowptr, srcids, dinv, (uint2*)h2, N);

    // output head + log_softmax (h2 bf16)
    out_kernel<<<(N + 255) / 256, 256, 0, stream>>>((const uint4*)h2, Wo, bo, out, N);
    (void)ws_size; (void)n_in; (void)out_size; (void)HID1;
}

// Round 8
// 264.461 us; speedup vs baseline: 1.6831x; 1.0941x over previous
//
#include <hip/hip_runtime.h>
#include <hip/hip_bf16.h>

typedef unsigned short u16;
typedef unsigned int u32;
typedef __attribute__((ext_vector_type(8))) short bf16x8;   // 8 bf16 (4 VGPRs)
typedef __attribute__((ext_vector_type(4))) float f32x4;
typedef __attribute__((ext_vector_type(4))) u16 u16x4;

__device__ __forceinline__ u16 f2bf(float f) {
    union { float f; u32 u; } v; v.f = f;
    u32 r = v.u + 0x7FFF + ((v.u >> 16) & 1);   // RNE
    return (u16)(r >> 16);
}
__device__ __forceinline__ float bf_lo(u32 u) {
    union { u32 u; float f; } v; v.u = u << 16; return v.f;
}
__device__ __forceinline__ float bf_hi(u32 u) {
    union { u32 u; float f; } v; v.u = u & 0xFFFF0000u; return v.f;
}
__device__ __forceinline__ u32 pack2(float a, float b) {
    return (u32)f2bf(a) | ((u32)f2bf(b) << 16);
}

#define NB1 16     // super-buckets (stage 1)
#define NB2 256    // final buckets
#define SPAN 32    // rel-bucket span in stage 2 (<= 32)
#define CHUNK 8192 // edges per routing block (32 per thread)

// ---------------- stage 1: edges -> 16 dst-range super-buckets ----------------
// per-thread LDS histogram columns (no atomics), block scan, ONE reservation atomic
// per bucket per chunk (196 chunks -> 196 serialized RMWs per address, vs 6250 before)
__launch_bounds__(256)
__global__ void route1(const int* __restrict__ src, const int* __restrict__ dst, int E, int R1,
                       int* __restrict__ bcur, int2* __restrict__ bp, int bcap) {
    __shared__ int cnt[NB1][256];     // 16 KB
    __shared__ int lbase[NB1];
    const int tid = threadIdx.x;
    const int base = blockIdx.x * CHUNK;

#pragma unroll
    for (int b = 0; b < NB1; b++) cnt[b][tid] = 0;
    __syncthreads();

    // phase 1: count into own column (coalesced edge reads)
#pragma unroll 4
    for (int i = 0; i < CHUNK / 256; i++) {
        int e = base + i * 256 + tid;
        if (e < E) {
            int b = dst[e] / R1;
            cnt[b][tid]++;
        }
    }
    __syncthreads();

    // inclusive Hillis-Steele scan over thread columns, all buckets in parallel
    for (int offd = 1; offd < 256; offd <<= 1) {
        int u[NB1];
#pragma unroll
        for (int b = 0; b < NB1; b++) u[b] = (tid >= offd) ? cnt[b][tid - offd] : 0;
        __syncthreads();
#pragma unroll
        for (int b = 0; b < NB1; b++) cnt[b][tid] += u[b];
        __syncthreads();
    }

    if (tid < NB1) {
        int tot = cnt[tid][255];
        lbase[tid] = tot ? atomicAdd(&bcur[tid], tot) : 0;
    }
    int prev[NB1];
#pragma unroll
    for (int b = 0; b < NB1; b++) prev[b] = tid ? cnt[b][tid - 1] : 0;
    __syncthreads();
#pragma unroll
    for (int b = 0; b < NB1; b++) cnt[b][tid] = lbase[b] + prev[b];   // private cursor
    __syncthreads();

    // phase 3: route (private LDS cursor, no atomics)
#pragma unroll 4
    for (int i = 0; i < CHUNK / 256; i++) {
        int e = base + i * 256 + tid;
        if (e < E) {
            int d = dst[e], s = src[e];
            int b = d / R1;
            int pos = cnt[b][tid]++;
            if (pos < bcap) bp[(size_t)b * bcap + pos] = (int2){s, d};
        }
    }
}

// ---------------- stage 2: super-bucket -> 16 final buckets each (256 total) ----------------
__launch_bounds__(256)
__global__ void route2(const int2* __restrict__ bp1, const int* __restrict__ bcnt1, int bcap1,
                       int R1, int R2, int* __restrict__ bcur2, int2* __restrict__ bp2, int bcap2) {
    __shared__ int cnt[SPAN][256];    // 32 KB
    __shared__ int lbase[SPAN];
    const int sb = blockIdx.x & (NB1 - 1);
    const int t = blockIdx.x >> 4;
    const int tid = threadIdx.x;
    int total = bcnt1[sb];
    if (total > bcap1) total = bcap1;
    const int base = t * CHUNK;
    if (base >= total) return;                 // block-uniform
    const int f0 = (sb * R1) / R2;
    const int2* in = bp1 + (size_t)sb * bcap1;

#pragma unroll
    for (int b = 0; b < SPAN; b++) cnt[b][tid] = 0;
    __syncthreads();

#pragma unroll 4
    for (int i = 0; i < CHUNK / 256; i++) {
        int e = base + i * 256 + tid;
        if (e < total) {
            int rel = in[e].y / R2 - f0;       // span <= 17 < 32
            cnt[rel][tid]++;
        }
    }
    __syncthreads();

    for (int offd = 1; offd < 256; offd <<= 1) {
        int u[SPAN];
#pragma unroll
        for (int b = 0; b < SPAN; b++) u[b] = (tid >= offd) ? cnt[b][tid - offd] : 0;
        __syncthreads();
#pragma unroll
        for (int b = 0; b < SPAN; b++) cnt[b][tid] += u[b];
        __syncthreads();
    }

    if (tid < SPAN) {
        int tot = cnt[tid][255];
        lbase[tid] = tot ? atomicAdd(&bcur2[f0 + tid], tot) : 0;
    }
    int prev[SPAN];
#pragma unroll
    for (int b = 0; b < SPAN; b++) prev[b] = tid ? cnt[b][tid - 1] : 0;
    __syncthreads();
#pragma unroll
    for (int b = 0; b < SPAN; b++) cnt[b][tid] = lbase[b] + prev[b];
    __syncthreads();

#pragma unroll 4
    for (int i = 0; i < CHUNK / 256; i++) {
        int e = base + i * 256 + tid;
        if (e < total) {
            int2 p = in[e];
            int rel = p.y / R2 - f0;
            int pos = cnt[rel][tid]++;
            if (pos < bcap2) bp2[(size_t)(f0 + rel) * bcap2 + pos] = p;
        }
    }
}

// ---------------- exclusive scan of 256 bucket counts -> global srcids bases ----------------
__global__ void scan_vcnt(const int* __restrict__ bcnt2, int* __restrict__ vbase,
                          int* __restrict__ rowptr, int N, int E) {
    __shared__ int sd[NB2];
    const int t = threadIdx.x;
    int v = bcnt2[t];
    sd[t] = v;
    __syncthreads();
    for (int off = 1; off < NB2; off <<= 1) {
        int u = (t >= off) ? sd[t - off] : 0;
        __syncthreads();
        sd[t] += u;
        __syncthreads();
    }
    vbase[t] = sd[t] - v;   // exclusive
    if (t == NB2 - 1) rowptr[N] = E;
}

// ---------------- per-bucket CSR build: LDS histogram + scan + LDS-atomic fill ----------------
__launch_bounds__(256)
__global__ void build_csr(const int2* __restrict__ bp2, const int* __restrict__ bcnt2, int bcap2,
                          const int* __restrict__ vbase, int R2, int N,
                          int* __restrict__ rowptr, float* __restrict__ dinv,
                          int* __restrict__ srcids) {
    __shared__ int bins[1024];       // R2 <= 1024
    __shared__ int tsum[256];
    const int b = blockIdx.x;
    const int tid = threadIdx.x;
    const int lo = b * R2;
    int hi = lo + R2; if (hi > N) hi = N;
    const int nb = hi - lo;
    if (nb <= 0) return;
    int cnt = bcnt2[b];
    if (cnt > bcap2) cnt = bcap2;
    const int2* mine = bp2 + (size_t)b * bcap2;

    for (int i = tid; i < nb; i += 256) bins[i] = 0;
    __syncthreads();
    for (int i = tid; i < cnt; i += 256) {
        int2 p = mine[i];
        atomicAdd(&bins[p.y - lo], 1);
    }
    __syncthreads();

    const int base4 = tid * 4;
    int ex[4]; int run = 0;
#pragma unroll
    for (int k = 0; k < 4; k++) {
        int idx = base4 + k;
        if (idx < nb) {
            int c = bins[idx];
            dinv[lo + idx] = rsqrtf((float)c + 1.0f);
            ex[k] = run;
            run += c;
        }
    }
    tsum[tid] = run;
    __syncthreads();
    for (int off = 1; off < 256; off <<= 1) {
        int u = (tid >= off) ? tsum[tid - off] : 0;
        __syncthreads();
        tsum[tid] += u;
        __syncthreads();
    }
    const int toff = ((tid > 0) ? tsum[tid - 1] : 0) + vbase[b];
    __syncthreads();
#pragma unroll
    for (int k = 0; k < 4; k++) {
        int idx = base4 + k;
        if (idx < nb) {
            int st = toff + ex[k];
            bins[idx] = st;           // absolute fill cursor into srcids
            rowptr[lo + idx] = st;
        }
    }
    __syncthreads();
    for (int i = tid; i < cnt; i += 256) {
        int2 p = mine[i];
        int pos = atomicAdd(&bins[p.y - lo], 1);
        srcids[pos] = p.x;
    }
}

// ---------------- weight transpose+convert (both layers in one kernel) ----------------
__global__ void conv_w2(const float* __restrict__ W1, u16* __restrict__ B1, int K1, int N1,
                        const float* __restrict__ W2, u16* __restrict__ B2, int K2, int N2) {
    int i = blockIdx.x * 256 + threadIdx.x;
    int sz1 = K1 * N1;
    if (i < sz1) {
        int n = i / K1, k = i - n * K1;
        B1[i] = f2bf(W1[(size_t)k * N1 + n]);
    } else if (i - sz1 < K2 * N2) {
        int j = i - sz1;
        int n = j / K2, k = j - n * K2;
        B2[j] = f2bf(W2[(size_t)k * N2 + n]);
    }
}

// ---------------- MFMA bf16 GEMM: G[m][n] = bf16( (A @ Bt^T)[m][n] * dinv[m] ) ----------------
template <int K, int BN, int IFR, int JFR, int WM, int WN, bool ABF16>
__launch_bounds__(256)
__global__ void gemm_mfma(const void* __restrict__ Av, const u16* __restrict__ Bt,
                          const float* __restrict__ dinv, u16* __restrict__ G, int M) {
    constexpr int BM = 128, BK = 32;
    __shared__ u16 As[BM][BK];   // 64 B rows -> conflict-free b128 frag reads
    __shared__ u16 Bs[BN][BK];
    const int tid = threadIdx.x;
    const int lane = tid & 63, wave = tid >> 6;
    const int r = lane & 15, g = lane >> 4;
    const int wm = wave % WM, wn = wave / WM;
    const int m0 = blockIdx.x * BM;

    f32x4 acc[IFR][JFR];
#pragma unroll
    for (int i = 0; i < IFR; i++)
#pragma unroll
        for (int j = 0; j < JFR; j++) acc[i][j] = (f32x4){0.f, 0.f, 0.f, 0.f};

    for (int k0 = 0; k0 < K; k0 += BK) {
#pragma unroll
        for (int p = 0; p < 4; p++) {
            int q = tid + p * 256;
            int row = q >> 3, kq = (q & 7) << 2;
            int gr = m0 + row; if (gr >= M) gr = M - 1;   // clamp; stores guarded
            if constexpr (ABF16) {
                const u16* A = (const u16*)Av;
                *(u16x4*)&As[row][kq] = *(const u16x4*)(A + (size_t)gr * K + k0 + kq);
            } else {
                const float* A = (const float*)Av;
                float4 a = *(const float4*)(A + (size_t)gr * K + k0 + kq);
                u16x4 v = { f2bf(a.x), f2bf(a.y), f2bf(a.z), f2bf(a.w) };
                *(u16x4*)&As[row][kq] = v;
            }
        }
#pragma unroll
        for (int p = 0; p < BN / 32; p++) {
            int q = tid + p * 256;
            int row = q >> 3, kq = (q & 7) << 2;
            *(u16x4*)&Bs[row][kq] = *(const u16x4*)(Bt + (size_t)row * K + k0 + kq);
        }
        __syncthreads();

        bf16x8 af[IFR], bfr[JFR];
#pragma unroll
        for (int i = 0; i < IFR; i++)
            af[i] = *(const bf16x8*)&As[wm * (IFR * 16) + i * 16 + r][g * 8];
#pragma unroll
        for (int j = 0; j < JFR; j++)
            bfr[j] = *(const bf16x8*)&Bs[wn * (JFR * 16) + j * 16 + r][g * 8];
#pragma unroll
        for (int i = 0; i < IFR; i++)
#pragma unroll
            for (int j = 0; j < JFR; j++)
                acc[i][j] = __builtin_amdgcn_mfma_f32_16x16x32_bf16(af[i], bfr[j], acc[i][j], 0, 0, 0);
        __syncthreads();
    }

    // C/D layout: col=lane&15, row=(lane>>4)*4+reg
#pragma unroll
    for (int i = 0; i < IFR; i++) {
#pragma unroll
        for (int t = 0; t < 4; t++) {
            int row = m0 + wm * (IFR * 16) + i * 16 + g * 4 + t;
            if (row < M) {
                float dn = dinv[row];
#pragma unroll
                for (int j = 0; j < JFR; j++) {
                    int col = wn * (JFR * 16) + j * 16 + r;
                    G[(size_t)row * BN + col] = f2bf(acc[i][j][t] * dn);
                }
            }
        }
    }
}

// ---------------- agg F=128: one 16-lane quarter per node; lane owns 16B slice ----------------
__launch_bounds__(256)
__global__ void agg128(const uint4* __restrict__ g1, const float4* __restrict__ bias,
                       const int* __restrict__ rowptr, const int* __restrict__ srcids,
                       const float* __restrict__ dinv, uint4* __restrict__ h1, int n) {
    const int tq = threadIdx.x >> 4;       // quarter within block [0,16)
    const int c  = threadIdx.x & 15;       // 16B slice index
    const int node = blockIdx.x * 16 + tq;
    if (node >= n) return;
    const float dn = dinv[node];
    uint4 sv = g1[(size_t)node * 16 + c];  // self
    float a0 = bf_lo(sv.x), a1 = bf_hi(sv.x), a2 = bf_lo(sv.y), a3 = bf_hi(sv.y);
    float a4 = bf_lo(sv.z), a5 = bf_hi(sv.z), a6 = bf_lo(sv.w), a7 = bf_hi(sv.w);
    const int end = rowptr[node + 1];
    int j = rowptr[node];
    for (; j + 3 < end; j += 4) {          // 4 gathers in flight per quarter
        int s0 = srcids[j], s1 = srcids[j + 1], s2 = srcids[j + 2], s3 = srcids[j + 3];
        uint4 v0 = g1[(size_t)s0 * 16 + c];
        uint4 v1 = g1[(size_t)s1 * 16 + c];
        uint4 v2 = g1[(size_t)s2 * 16 + c];
        uint4 v3 = g1[(size_t)s3 * 16 + c];
        a0 += (bf_lo(v0.x) + bf_lo(v1.x)) + (bf_lo(v2.x) + bf_lo(v3.x));
        a1 += (bf_hi(v0.x) + bf_hi(v1.x)) + (bf_hi(v2.x) + bf_hi(v3.x));
        a2 += (bf_lo(v0.y) + bf_lo(v1.y)) + (bf_lo(v2.y) + bf_lo(v3.y));
        a3 += (bf_hi(v0.y) + bf_hi(v1.y)) + (bf_hi(v2.y) + bf_hi(v3.y));
        a4 += (bf_lo(v0.z) + bf_lo(v1.z)) + (bf_lo(v2.z) + bf_lo(v3.z));
        a5 += (bf_hi(v0.z) + bf_hi(v1.z)) + (bf_hi(v2.z) + bf_hi(v3.z));
        a6 += (bf_lo(v0.w) + bf_lo(v1.w)) + (bf_lo(v2.w) + bf_lo(v3.w));
        a7 += (bf_hi(v0.w) + bf_hi(v1.w)) + (bf_hi(v2.w) + bf_hi(v3.w));
    }
    for (; j < end; j++) {
        uint4 v = g1[(size_t)srcids[j] * 16 + c];
        a0 += bf_lo(v.x); a1 += bf_hi(v.x); a2 += bf_lo(v.y); a3 += bf_hi(v.y);
        a4 += bf_lo(v.z); a5 += bf_hi(v.z); a6 += bf_lo(v.w); a7 += bf_hi(v.w);
    }
    float4 b0 = bias[c * 2], b1v = bias[c * 2 + 1];
    uint4 w;
    w.x = pack2(fmaxf(a0 * dn + b0.x, 0.f), fmaxf(a1 * dn + b0.y, 0.f));
    w.y = pack2(fmaxf(a2 * dn + b0.z, 0.f), fmaxf(a3 * dn + b0.w, 0.f));
    w.z = pack2(fmaxf(a4 * dn + b1v.x, 0.f), fmaxf(a5 * dn + b1v.y, 0.f));
    w.w = pack2(fmaxf(a6 * dn + b1v.z, 0.f), fmaxf(a7 * dn + b1v.w, 0.f));
    h1[(size_t)node * 16 + c] = w;
}

// ---------------- agg F=64: one 16-lane quarter per node; lane owns 8B slice; bf16 out ----------------
__launch_bounds__(256)
__global__ void agg64(const uint2* __restrict__ g2, const float4* __restrict__ bias,
                      const int* __restrict__ rowptr, const int* __restrict__ srcids,
                      const float* __restrict__ dinv, uint2* __restrict__ h2, int n) {
    const int tq = threadIdx.x >> 4;
    const int c  = threadIdx.x & 15;
    const int node = blockIdx.x * 16 + tq;
    if (node >= n) return;
    const float dn = dinv[node];
    uint2 sv = g2[(size_t)node * 16 + c];
    float a0 = bf_lo(sv.x), a1 = bf_hi(sv.x), a2 = bf_lo(sv.y), a3 = bf_hi(sv.y);
    const int end = rowptr[node + 1];
    int j = rowptr[node];
    for (; j + 3 < end; j += 4) {
        int s0 = srcids[j], s1 = srcids[j + 1], s2 = srcids[j + 2], s3 = srcids[j + 3];
        uint2 v0 = g2[(size_t)s0 * 16 + c];
        uint2 v1 = g2[(size_t)s1 * 16 + c];
        uint2 v2 = g2[(size_t)s2 * 16 + c];
        uint2 v3 = g2[(size_t)s3 * 16 + c];
        a0 += (bf_lo(v0.x) + bf_lo(v1.x)) + (bf_lo(v2.x) + bf_lo(v3.x));
        a1 += (bf_hi(v0.x) + bf_hi(v1.x)) + (bf_hi(v2.x) + bf_hi(v3.x));
        a2 += (bf_lo(v0.y) + bf_lo(v1.y)) + (bf_lo(v2.y) + bf_lo(v3.y));
        a3 += (bf_hi(v0.y) + bf_hi(v1.y)) + (bf_hi(v2.y) + bf_hi(v3.y));
    }
    for (; j < end; j++) {
        uint2 v = g2[(size_t)srcids[j] * 16 + c];
        a0 += bf_lo(v.x); a1 += bf_hi(v.x); a2 += bf_lo(v.y); a3 += bf_hi(v.y);
    }
    float4 bb = bias[c];
    uint2 w;
    w.x = pack2(a0 * dn + bb.x, a1 * dn + bb.y);
    w.y = pack2(a2 * dn + bb.z, a3 * dn + bb.w);
    h2[(size_t)node * 16 + c] = w;
}

// ---------------- final: out = log_softmax(h2 @ Wo + bo), h2 bf16 ----------------
__launch_bounds__(256)
__global__ void out_kernel(const uint4* __restrict__ h2, const float* __restrict__ Wo,
                           const float* __restrict__ bo, float* __restrict__ out, int n) {
    __shared__ float Ws[64 * 40];
    __shared__ float bs[40];
    for (int i = threadIdx.x; i < 64 * 40; i += 256) Ws[i] = Wo[i];
    if (threadIdx.x < 40) bs[threadIdx.x] = bo[threadIdx.x];
    __syncthreads();

    int row = blockIdx.x * 256 + threadIdx.x;
    if (row >= n) return;

    float acc[40];
#pragma unroll
    for (int j = 0; j < 40; j++) acc[j] = 0.f;

    const uint4* hr = h2 + (size_t)row * 8;   // 64 bf16 = 8 x uint4
#pragma unroll 2
    for (int k8 = 0; k8 < 8; k8++) {
        uint4 v = hr[k8];
        float hv[8] = { bf_lo(v.x), bf_hi(v.x), bf_lo(v.y), bf_hi(v.y),
                        bf_lo(v.z), bf_hi(v.z), bf_lo(v.w), bf_hi(v.w) };
#pragma unroll
        for (int u = 0; u < 8; u++) {
            float a = hv[u];
            const float* wrow = &Ws[(k8 * 8 + u) * 40];
#pragma unroll
            for (int j = 0; j < 40; j++) acc[j] += a * wrow[j];
        }
    }

    float m = -1e30f;
#pragma unroll
    for (int j = 0; j < 40; j++) { acc[j] += bs[j]; m = fmaxf(m, acc[j]); }
    float s = 0.f;
#pragma unroll
    for (int j = 0; j < 40; j++) s += expf(acc[j] - m);
    float lse = m + logf(s);

    float* op = out + (size_t)row * 40;
#pragma unroll
    for (int j4 = 0; j4 < 10; j4++) {
        float4 w = { acc[j4 * 4] - lse, acc[j4 * 4 + 1] - lse,
                     acc[j4 * 4 + 2] - lse, acc[j4 * 4 + 3] - lse };
        *(float4*)(op + j4 * 4) = w;
    }
}

extern "C" void kernel_launch(void* const* d_in, const int* in_sizes, int n_in,
                              void* d_out, int out_size, void* d_ws, size_t ws_size,
                              hipStream_t stream) {
    const float* x  = (const float*)d_in[0];
    const int*   ei = (const int*)d_in[1];
    const float* W1 = (const float*)d_in[2];
    const float* b1 = (const float*)d_in[3];
    const float* W2 = (const float*)d_in[4];
    const float* b2 = (const float*)d_in[5];
    const float* Wo = (const float*)d_in[6];
    const float* bo = (const float*)d_in[7];
    float* out = (float*)d_out;

    const int HID  = in_sizes[3];           // 128
    const int IN   = in_sizes[2] / HID;     // 256
    const int HID1 = in_sizes[5];           // 64
    const int N = in_sizes[0] / IN;         // 100000
    const int E = in_sizes[1] / 2;          // 1600000
    const int* src = ei;
    const int* dst = ei + E;

    const int R1 = (N + NB1 - 1) / NB1;     // 6250
    const int R2 = (N + NB2 - 1) / NB2;     // 391
    const int bcap1 = E / NB1 + 8192;       // ~108K
    const int bcap2 = E / NB2 + 2048;       // ~8.3K (>20 sigma)

    char* ws = (char*)d_ws;
    size_t off = 0;
    auto alloc = [&](size_t bytes) -> void* {
        void* p = ws + off;
        off += (bytes + 255) / 256 * 256;
        return p;
    };
    float* dinv   = (float*)alloc((size_t)N * 4);
    int*   rowptr = (int*)alloc((size_t)(N + 1) * 4);
    int*   atom   = (int*)alloc((NB1 + NB2) * 4);          // bcur1 | bcur2 (one memset)
    int*   bcur1  = atom;
    int*   bcur2  = atom + NB1;
    int*   vbase  = (int*)alloc(NB2 * 4);
    int*   srcids = (int*)alloc((size_t)E * 4);
    u16*   W1t    = (u16*)alloc((size_t)IN * HID * 2);     // [128][256] bf16
    u16*   W2t    = (u16*)alloc((size_t)HID * HID1 * 2);   // [64][128] bf16
    // shared region: bp1+bp2 (CSR build) -> g1 (gemm1/agg128) -> h2 (agg64/out); sequential
    size_t bp1Bytes = (size_t)NB1 * bcap1 * 8;
    size_t bp2Bytes = (size_t)NB2 * bcap2 * 8;
    size_t sharedBytes = bp1Bytes + bp2Bytes;              // ~31 MB
    size_t gBytes = (size_t)N * HID * 2;                   // 25.6 MB
    if (gBytes > sharedBytes) sharedBytes = gBytes;
    char*  shared = (char*)alloc(sharedBytes);
    int2*  bp1    = (int2*)shared;
    int2*  bp2    = (int2*)(shared + bp1Bytes);
    u16*   g1     = (u16*)shared;
    u16*   h2     = (u16*)shared;                          // bf16 [N][64]
    u16*   h1     = (u16*)alloc((size_t)N * HID * 2);      // bf16 [N][128]
    u16*   g2     = (u16*)alloc((size_t)N * HID1 * 2);     // bf16 [N][64]

    // ---- CSR build: contention-free chunked routing ----
    hipMemsetAsync(atom, 0, (NB1 + NB2) * 4, stream);
    const int nchunk1 = (E + CHUNK - 1) / CHUNK;           // 196
    route1<<<nchunk1, 256, 0, stream>>>(src, dst, E, R1, bcur1, bp1, bcap1);
    const int nchunk2 = (bcap1 + CHUNK - 1) / CHUNK;       // 14
    route2<<<NB1 * nchunk2, 256, 0, stream>>>(bp1, bcur1, bcap1, R1, R2, bcur2, bp2, bcap2);
    scan_vcnt<<<1, NB2, 0, stream>>>(bcur2, vbase, rowptr, N, E);
    build_csr<<<NB2, 256, 0, stream>>>(bp2, bcur2, bcap2, vbase, R2, N, rowptr, dinv, srcids);

    // weights -> bf16 transposed
    conv_w2<<<(IN * HID + HID * HID1 + 255) / 256, 256, 0, stream>>>(
        W1, W1t, IN, HID, W2, W2t, HID, HID1);

    const int gblocks = (N + 127) / 128;
    // layer 1: g1 = bf16((x @ W1) * dinv); h1 = bf16(relu(agg(g1)*dinv + b1))
    gemm_mfma<256, 128, 4, 4, 2, 2, false><<<gblocks, 256, 0, stream>>>(x, W1t, dinv, g1, N);
    agg128<<<(N + 15) / 16, 256, 0, stream>>>((const uint4*)g1, (const float4*)b1,
                                              rowptr, srcids, dinv, (uint4*)h1, N);

    // layer 2: g2 = bf16((h1 @ W2) * dinv); h2 = bf16(agg(g2)*dinv + b2)
    gemm_mfma<128, 64, 2, 4, 4, 1, true><<<gblocks, 256, 0, stream>>>(h1, W2t, dinv, g2, N);
    agg64<<<(N + 15) / 16, 256, 0, stream>>>((const uint2*)g2, (const float4*)b2,
                                             rowptr, srcids, dinv, (uint2*)h2, N);

    // output head + log_softmax (h2 bf16)
    out_kernel<<<(N + 255) / 256, 256, 0, stream>>>((const uint4*)h2, Wo, bo, out, N);
    (void)ws_size; (void)n_in; (void)out_size; (void)HID1;
}

// Round 10
// 256.153 us; speedup vs baseline: 1.7377x; 1.0324x over previous
//
#include <hip/hip_runtime.h>
#include <hip/hip_bf16.h>

typedef unsigned short u16;
typedef unsigned int u32;
typedef __attribute__((ext_vector_type(8))) short bf16x8;   // 8 bf16 (4 VGPRs)
typedef __attribute__((ext_vector_type(4))) float f32x4;
typedef __attribute__((ext_vector_type(4))) u16 u16x4;

__device__ __forceinline__ u16 f2bf(float f) {
    union { float f; u32 u; } v; v.f = f;
    u32 r = v.u + 0x7FFF + ((v.u >> 16) & 1);   // RNE
    return (u16)(r >> 16);
}
__device__ __forceinline__ float bf_lo(u32 u) {
    union { u32 u; float f; } v; v.u = u << 16; return v.f;
}
__device__ __forceinline__ float bf_hi(u32 u) {
    union { u32 u; float f; } v; v.u = u & 0xFFFF0000u; return v.f;
}
__device__ __forceinline__ u32 pack2(float a, float b) {
    return (u32)f2bf(a) | ((u32)f2bf(b) << 16);
}

#define NB1 16     // super-buckets (stage 1)
#define NB2 256    // final buckets
#define SPAN 17    // rel-bucket span in stage 2 (max actual = 17)
#define CHUNK 8192 // edges per routing block (32 per thread)

// ---------------- stage 1: edges -> 16 dst-range super-buckets ----------------
__launch_bounds__(256)
__global__ void route1(const int* __restrict__ src, const int* __restrict__ dst, int E, int R1,
                       int* __restrict__ bcur, int2* __restrict__ bp, int bcap) {
    __shared__ int cnt[NB1][256];     // 16 KB
    __shared__ int lbase[NB1];
    const int tid = threadIdx.x;
    const int base = blockIdx.x * CHUNK;

#pragma unroll
    for (int b = 0; b < NB1; b++) cnt[b][tid] = 0;
    __syncthreads();

#pragma unroll 4
    for (int i = 0; i < CHUNK / 256; i++) {
        int e = base + i * 256 + tid;
        if (e < E) {
            int b = dst[e] / R1;
            cnt[b][tid]++;
        }
    }
    __syncthreads();

    for (int offd = 1; offd < 256; offd <<= 1) {
        int u[NB1];
#pragma unroll
        for (int b = 0; b < NB1; b++) u[b] = (tid >= offd) ? cnt[b][tid - offd] : 0;
        __syncthreads();
#pragma unroll
        for (int b = 0; b < NB1; b++) cnt[b][tid] += u[b];
        __syncthreads();
    }

    if (tid < NB1) {
        int tot = cnt[tid][255];
        lbase[tid] = tot ? atomicAdd(&bcur[tid], tot) : 0;
    }
    int prev[NB1];
#pragma unroll
    for (int b = 0; b < NB1; b++) prev[b] = tid ? cnt[b][tid - 1] : 0;
    __syncthreads();
#pragma unroll
    for (int b = 0; b < NB1; b++) cnt[b][tid] = lbase[b] + prev[b];   // private cursor
    __syncthreads();

#pragma unroll 4
    for (int i = 0; i < CHUNK / 256; i++) {
        int e = base + i * 256 + tid;
        if (e < E) {
            int d = dst[e], s = src[e];
            int b = d / R1;
            int pos = cnt[b][tid]++;
            if (pos < bcap) bp[(size_t)b * bcap + pos] = (int2){s, d};
        }
    }
}

// ---------------- stage 2: super-bucket -> final buckets (256 total) ----------------
__launch_bounds__(256)
__global__ void route2(const int2* __restrict__ bp1, const int* __restrict__ bcnt1, int bcap1,
                       int R1, int R2, int* __restrict__ bcur2, int2* __restrict__ bp2, int bcap2) {
    __shared__ int cnt[SPAN][256];
    __shared__ int lbase[SPAN];
    const int sb = blockIdx.x & (NB1 - 1);
    const int t = blockIdx.x >> 4;
    const int tid = threadIdx.x;
    int total = bcnt1[sb];
    if (total > bcap1) total = bcap1;
    const int base = t * CHUNK;
    if (base >= total) return;                 // block-uniform
    const int f0 = (sb * R1) / R2;
    const int2* in = bp1 + (size_t)sb * bcap1;

#pragma unroll
    for (int b = 0; b < SPAN; b++) cnt[b][tid] = 0;
    __syncthreads();

#pragma unroll 4
    for (int i = 0; i < CHUNK / 256; i++) {
        int e = base + i * 256 + tid;
        if (e < total) {
            int rel = in[e].y / R2 - f0;       // <= 16
            cnt[rel][tid]++;
        }
    }
    __syncthreads();

    for (int offd = 1; offd < 256; offd <<= 1) {
        int u[SPAN];
#pragma unroll
        for (int b = 0; b < SPAN; b++) u[b] = (tid >= offd) ? cnt[b][tid - offd] : 0;
        __syncthreads();
#pragma unroll
        for (int b = 0; b < SPAN; b++) cnt[b][tid] += u[b];
        __syncthreads();
    }

    if (tid < SPAN) {
        int tot = cnt[tid][255];
        lbase[tid] = tot ? atomicAdd(&bcur2[f0 + tid], tot) : 0;
    }
    int prev[SPAN];
#pragma unroll
    for (int b = 0; b < SPAN; b++) prev[b] = tid ? cnt[b][tid - 1] : 0;
    __syncthreads();
#pragma unroll
    for (int b = 0; b < SPAN; b++) cnt[b][tid] = lbase[b] + prev[b];
    __syncthreads();

#pragma unroll 4
    for (int i = 0; i < CHUNK / 256; i++) {
        int e = base + i * 256 + tid;
        if (e < total) {
            int2 p = in[e];
            int rel = p.y / R2 - f0;
            int pos = cnt[rel][tid]++;
            if (pos < bcap2) bp2[(size_t)(f0 + rel) * bcap2 + pos] = p;
        }
    }
}

// ---------------- per-bucket CSR build with 4-aligned padded rows ----------------
// rs/re per node; segments padded to x4 with sentinel src = N (zero row); fixed
// per-bucket srcids regions (b * sreg, sreg % 4 == 0 so every segment is int4-aligned)
__launch_bounds__(256)
__global__ void build_csr(const int2* __restrict__ bp2, const int* __restrict__ bcnt2, int bcap2,
                          int sreg, int R2, int N,
                          int* __restrict__ rs, int* __restrict__ re,
                          float* __restrict__ dinv, int* __restrict__ srcids) {
    __shared__ int bins[1024];       // R2 <= 1024
    __shared__ int tsum[256];
    const int b = blockIdx.x;
    const int tid = threadIdx.x;
    const int lo = b * R2;
    int hi = lo + R2; if (hi > N) hi = N;
    const int nb = hi - lo;
    if (nb <= 0) return;
    int cnt = bcnt2[b];
    if (cnt > bcap2) cnt = bcap2;
    const int2* mine = bp2 + (size_t)b * bcap2;

    for (int i = tid; i < nb; i += 256) bins[i] = 0;
    __syncthreads();
    for (int i = tid; i < cnt; i += 256) {
        int2 p = mine[i];
        atomicAdd(&bins[p.y - lo], 1);
    }
    __syncthreads();

    const int base4 = tid * 4;
    int creal[4], cpad[4], ex[4];
    int run = 0;
#pragma unroll
    for (int k = 0; k < 4; k++) {
        int idx = base4 + k;
        creal[k] = 0; cpad[k] = 0; ex[k] = 0;
        if (idx < nb) {
            int c = bins[idx];
            creal[k] = c;
            cpad[k] = (c + 3) & ~3;
            dinv[lo + idx] = rsqrtf((float)c + 1.0f);
            ex[k] = run;
            run += cpad[k];
        }
    }
    tsum[tid] = run;
    __syncthreads();
    for (int off = 1; off < 256; off <<= 1) {
        int u = (tid >= off) ? tsum[tid - off] : 0;
        __syncthreads();
        tsum[tid] += u;
        __syncthreads();
    }
    const int toff = ((tid > 0) ? tsum[tid - 1] : 0) + b * sreg;
    __syncthreads();
#pragma unroll
    for (int k = 0; k < 4; k++) {
        int idx = base4 + k;
        if (idx < nb) {
            int st = toff + ex[k];
            bins[idx] = st;                    // absolute fill cursor
            rs[lo + idx] = st;
            re[lo + idx] = st + cpad[k];
            for (int q = creal[k]; q < cpad[k]; q++) srcids[st + q] = N;  // sentinel
        }
    }
    __syncthreads();
    for (int i = tid; i < cnt; i += 256) {
        int2 p = mine[i];
        int pos = atomicAdd(&bins[p.y - lo], 1);
        srcids[pos] = p.x;
    }
}

// ---------------- zero sentinel rows (row N of g1 and g2) ----------------
__global__ void zero_pad(u32* __restrict__ g1, u32* __restrict__ g2, int N) {
    int t = threadIdx.x;
    if (t < 64) g1[(size_t)N * 64 + t] = 0;
    if (t < 32) g2[(size_t)N * 32 + t] = 0;
}

// ---------------- weight transpose+convert (both layers in one kernel) ----------------
__global__ void conv_w2(const float* __restrict__ W1, u16* __restrict__ B1, int K1, int N1,
                        const float* __restrict__ W2, u16* __restrict__ B2, int K2, int N2) {
    int i = blockIdx.x * 256 + threadIdx.x;
    int sz1 = K1 * N1;
    if (i < sz1) {
        int n = i / K1, k = i - n * K1;
        B1[i] = f2bf(W1[(size_t)k * N1 + n]);
    } else if (i - sz1 < K2 * N2) {
        int j = i - sz1;
        int n = j / K2, k = j - n * K2;
        B2[j] = f2bf(W2[(size_t)k * N2 + n]);
    }
}

// ---------------- MFMA bf16 GEMM: G[m][n] = bf16( (A @ Bt^T)[m][n] * dinv[m] ) ----------------
template <int K, int BN, int IFR, int JFR, int WM, int WN, bool ABF16>
__launch_bounds__(256)
__global__ void gemm_mfma(const void* __restrict__ Av, const u16* __restrict__ Bt,
                          const float* __restrict__ dinv, u16* __restrict__ G, int M) {
    constexpr int BM = 128, BK = 32;
    __shared__ u16 As[BM][BK];   // 64 B rows -> conflict-free b128 frag reads
    __shared__ u16 Bs[BN][BK];
    const int tid = threadIdx.x;
    const int lane = tid & 63, wave = tid >> 6;
    const int r = lane & 15, g = lane >> 4;
    const int wm = wave % WM, wn = wave / WM;
    const int m0 = blockIdx.x * BM;

    f32x4 acc[IFR][JFR];
#pragma unroll
    for (int i = 0; i < IFR; i++)
#pragma unroll
        for (int j = 0; j < JFR; j++) acc[i][j] = (f32x4){0.f, 0.f, 0.f, 0.f};

    for (int k0 = 0; k0 < K; k0 += BK) {
#pragma unroll
        for (int p = 0; p < 4; p++) {
            int q = tid + p * 256;
            int row = q >> 3, kq = (q & 7) << 2;
            int gr = m0 + row; if (gr >= M) gr = M - 1;   // clamp; stores guarded
            if constexpr (ABF16) {
                const u16* A = (const u16*)Av;
                *(u16x4*)&As[row][kq] = *(const u16x4*)(A + (size_t)gr * K + k0 + kq);
            } else {
                const float* A = (const float*)Av;
                float4 a = *(const float4*)(A + (size_t)gr * K + k0 + kq);
                u16x4 v = { f2bf(a.x), f2bf(a.y), f2bf(a.z), f2bf(a.w) };
                *(u16x4*)&As[row][kq] = v;
            }
        }
#pragma unroll
        for (int p = 0; p < BN / 32; p++) {
            int q = tid + p * 256;
            int row = q >> 3, kq = (q & 7) << 2;
            *(u16x4*)&Bs[row][kq] = *(const u16x4*)(Bt + (size_t)row * K + k0 + kq);
        }
        __syncthreads();

        bf16x8 af[IFR], bfr[JFR];
#pragma unroll
        for (int i = 0; i < IFR; i++)
            af[i] = *(const bf16x8*)&As[wm * (IFR * 16) + i * 16 + r][g * 8];
#pragma unroll
        for (int j = 0; j < JFR; j++)
            bfr[j] = *(const bf16x8*)&Bs[wn * (JFR * 16) + j * 16 + r][g * 8];
#pragma unroll
        for (int i = 0; i < IFR; i++)
#pragma unroll
            for (int j = 0; j < JFR; j++)
                acc[i][j] = __builtin_amdgcn_mfma_f32_16x16x32_bf16(af[i], bfr[j], acc[i][j], 0, 0, 0);
        __syncthreads();
    }

    // C/D layout: col=lane&15, row=(lane>>4)*4+reg
#pragma unroll
    for (int i = 0; i < IFR; i++) {
#pragma unroll
        for (int t = 0; t < 4; t++) {
            int row = m0 + wm * (IFR * 16) + i * 16 + g * 4 + t;
            if (row < M) {
                float dn = dinv[row];
#pragma unroll
                for (int j = 0; j < JFR; j++) {
                    int col = wn * (JFR * 16) + j * 16 + r;
                    G[(size_t)row * BN + col] = f2bf(acc[i][j][t] * dn);
                }
            }
        }
    }
}

#define ACC8(v) { a0 += bf_lo(v.x); a1 += bf_hi(v.x); a2 += bf_lo(v.y); a3 += bf_hi(v.y); \
                  a4 += bf_lo(v.z); a5 += bf_hi(v.z); a6 += bf_lo(v.w); a7 += bf_hi(v.w); }

// ---------------- agg F=128: 16-lane quarter per node; pipelined int4 index loads ----------------
__launch_bounds__(256)
__global__ void agg128(const uint4* __restrict__ g1, const float4* __restrict__ bias,
                       const int* __restrict__ rs, const int* __restrict__ re,
                       const int* __restrict__ srcids, const float* __restrict__ dinv,
                       uint4* __restrict__ h1, int n) {
    const int tq = threadIdx.x >> 4;       // quarter [0,16)
    const int c  = threadIdx.x & 15;       // 16B slice
    const int node = blockIdx.x * 16 + tq;
    if (node >= n) return;
    const float dn = dinv[node];
    uint4 sv = g1[(size_t)node * 16 + c];
    float a0 = bf_lo(sv.x), a1 = bf_hi(sv.x), a2 = bf_lo(sv.y), a3 = bf_hi(sv.y);
    float a4 = bf_lo(sv.z), a5 = bf_hi(sv.z), a6 = bf_lo(sv.w), a7 = bf_hi(sv.w);

    int j = rs[node] >> 2;                 // int4-granular (segments 4-aligned+padded)
    const int jend = re[node] >> 2;
    const int4* ip = (const int4*)srcids;
    if (j < jend) {
        int4 idx = ip[j];
        for (++j; j < jend; ++j) {
            uint4 v0 = g1[(size_t)idx.x * 16 + c];
            uint4 v1 = g1[(size_t)idx.y * 16 + c];
            uint4 v2 = g1[(size_t)idx.z * 16 + c];
            uint4 v3 = g1[(size_t)idx.w * 16 + c];
            int4 nxt = ip[j];              // prefetch next indices under the gathers
            ACC8(v0); ACC8(v1); ACC8(v2); ACC8(v3);
            idx = nxt;
        }
        uint4 v0 = g1[(size_t)idx.x * 16 + c];
        uint4 v1 = g1[(size_t)idx.y * 16 + c];
        uint4 v2 = g1[(size_t)idx.z * 16 + c];
        uint4 v3 = g1[(size_t)idx.w * 16 + c];
        ACC8(v0); ACC8(v1); ACC8(v2); ACC8(v3);
    }

    float4 b0 = bias[c * 2], b1v = bias[c * 2 + 1];
    uint4 w;
    w.x = pack2(fmaxf(a0 * dn + b0.x, 0.f), fmaxf(a1 * dn + b0.y, 0.f));
    w.y = pack2(fmaxf(a2 * dn + b0.z, 0.f), fmaxf(a3 * dn + b0.w, 0.f));
    w.z = pack2(fmaxf(a4 * dn + b1v.x, 0.f), fmaxf(a5 * dn + b1v.y, 0.f));
    w.w = pack2(fmaxf(a6 * dn + b1v.z, 0.f), fmaxf(a7 * dn + b1v.w, 0.f));
    h1[(size_t)node * 16 + c] = w;
}

// ---------------- agg F=64: 16-lane quarter per node; pipelined int4 index loads ----------------
__launch_bounds__(256)
__global__ void agg64(const uint2* __restrict__ g2, const float4* __restrict__ bias,
                      const int* __restrict__ rs, const int* __restrict__ re,
                      const int* __restrict__ srcids, const float* __restrict__ dinv,
                      uint2* __restrict__ h2, int n) {
    const int tq = threadIdx.x >> 4;
    const int c  = threadIdx.x & 15;
    const int node = blockIdx.x * 16 + tq;
    if (node >= n) return;
    const float dn = dinv[node];
    uint2 sv = g2[(size_t)node * 16 + c];
    float a0 = bf_lo(sv.x), a1 = bf_hi(sv.x), a2 = bf_lo(sv.y), a3 = bf_hi(sv.y);

    int j = rs[node] >> 2;
    const int jend = re[node] >> 2;
    const int4* ip = (const int4*)srcids;
    if (j < jend) {
        int4 idx = ip[j];
        for (++j; j < jend; ++j) {
            uint2 v0 = g2[(size_t)idx.x * 16 + c];
            uint2 v1 = g2[(size_t)idx.y * 16 + c];
            uint2 v2 = g2[(size_t)idx.z * 16 + c];
            uint2 v3 = g2[(size_t)idx.w * 16 + c];
            int4 nxt = ip[j];
            a0 += (bf_lo(v0.x) + bf_lo(v1.x)) + (bf_lo(v2.x) + bf_lo(v3.x));
            a1 += (bf_hi(v0.x) + bf_hi(v1.x)) + (bf_hi(v2.x) + bf_hi(v3.x));
            a2 += (bf_lo(v0.y) + bf_lo(v1.y)) + (bf_lo(v2.y) + bf_lo(v3.y));
            a3 += (bf_hi(v0.y) + bf_hi(v1.y)) + (bf_hi(v2.y) + bf_hi(v3.y));
            idx = nxt;
        }
        uint2 v0 = g2[(size_t)idx.x * 16 + c];
        uint2 v1 = g2[(size_t)idx.y * 16 + c];
        uint2 v2 = g2[(size_t)idx.z * 16 + c];
        uint2 v3 = g2[(size_t)idx.w * 16 + c];
        a0 += (bf_lo(v0.x) + bf_lo(v1.x)) + (bf_lo(v2.x) + bf_lo(v3.x));
        a1 += (bf_hi(v0.x) + bf_hi(v1.x)) + (bf_hi(v2.x) + bf_hi(v3.x));
        a2 += (bf_lo(v0.y) + bf_lo(v1.y)) + (bf_lo(v2.y) + bf_lo(v3.y));
        a3 += (bf_hi(v0.y) + bf_hi(v1.y)) + (bf_hi(v2.y) + bf_hi(v3.y));
    }

    float4 bb = bias[c];
    uint2 w;
    w.x = pack2(a0 * dn + bb.x, a1 * dn + bb.y);
    w.y = pack2(a2 * dn + bb.z, a3 * dn + bb.w);
    h2[(size_t)node * 16 + c] = w;
}

// ---------------- final: out = log_softmax(h2 @ Wo + bo), h2 bf16 ----------------
__launch_bounds__(256)
__global__ void out_kernel(const uint4* __restrict__ h2, const float* __restrict__ Wo,
                           const float* __restrict__ bo, float* __restrict__ out, int n) {
    __shared__ float Ws[64 * 40];
    __shared__ float bs[40];
    for (int i = threadIdx.x; i < 64 * 40; i += 256) Ws[i] = Wo[i];
    if (threadIdx.x < 40) bs[threadIdx.x] = bo[threadIdx.x];
    __syncthreads();

    int row = blockIdx.x * 256 + threadIdx.x;
    if (row >= n) return;

    float acc[40];
#pragma unroll
    for (int j = 0; j < 40; j++) acc[j] = 0.f;

    const uint4* hr = h2 + (size_t)row * 8;   // 64 bf16 = 8 x uint4
#pragma unroll 2
    for (int k8 = 0; k8 < 8; k8++) {
        uint4 v = hr[k8];
        float hv[8] = { bf_lo(v.x), bf_hi(v.x), bf_lo(v.y), bf_hi(v.y),
                        bf_lo(v.z), bf_hi(v.z), bf_lo(v.w), bf_hi(v.w) };
#pragma unroll
        for (int u = 0; u < 8; u++) {
            float a = hv[u];
            const float* wrow = &Ws[(k8 * 8 + u) * 40];
#pragma unroll
            for (int j = 0; j < 40; j++) acc[j] += a * wrow[j];
        }
    }

    float m = -1e30f;
#pragma unroll
    for (int j = 0; j < 40; j++) { acc[j] += bs[j]; m = fmaxf(m, acc[j]); }
    float s = 0.f;
#pragma unroll
    for (int j = 0; j < 40; j++) s += expf(acc[j] - m);
    float lse = m + logf(s);

    float* op = out + (size_t)row * 40;
#pragma unroll
    for (int j4 = 0; j4 < 10; j4++) {
        float4 w = { acc[j4 * 4] - lse, acc[j4 * 4 + 1] - lse,
                     acc[j4 * 4 + 2] - lse, acc[j4 * 4 + 3] - lse };
        *(float4*)(op + j4 * 4) = w;
    }
}

extern "C" void kernel_launch(void* const* d_in, const int* in_sizes, int n_in,
                              void* d_out, int out_size, void* d_ws, size_t ws_size,
                              hipStream_t stream) {
    const float* x  = (const float*)d_in[0];
    const int*   ei = (const int*)d_in[1];
    const float* W1 = (const float*)d_in[2];
    const float* b1 = (const float*)d_in[3];
    const float* W2 = (const float*)d_in[4];
    const float* b2 = (const float*)d_in[5];
    const float* Wo = (const float*)d_in[6];
    const float* bo = (const float*)d_in[7];
    float* out = (float*)d_out;

    const int HID  = in_sizes[3];           // 128
    const int IN   = in_sizes[2] / HID;     // 256
    const int HID1 = in_sizes[5];           // 64
    const int N = in_sizes[0] / IN;         // 100000
    const int E = in_sizes[1] / 2;          // 1600000
    const int* src = ei;
    const int* dst = ei + E;

    const int R1 = (N + NB1 - 1) / NB1;     // 6250
    const int R2 = (N + NB2 - 1) / NB2;     // 391
    const int bcap1 = E / NB1 + 8192;       // ~108K
    const int bcap2 = E / NB2 + 2048;       // ~8.3K
    const int sreg  = (bcap2 + 3 * R2 + 32 + 3) & ~3;   // padded region stride, %4==0 (alignment invariant!)

    char* ws = (char*)d_ws;
    size_t off = 0;
    auto alloc = [&](size_t bytes) -> void* {
        void* p = ws + off;
        off += (bytes + 255) / 256 * 256;
        return p;
    };
    float* dinv   = (float*)alloc((size_t)N * 4);
    int*   rs     = (int*)alloc((size_t)N * 4);
    int*   re     = (int*)alloc((size_t)N * 4);
    int*   atom   = (int*)alloc((NB1 + NB2) * 4);          // bcur1 | bcur2 (one memset)
    int*   bcur1  = atom;
    int*   bcur2  = atom + NB1;
    int*   srcids = (int*)alloc((size_t)NB2 * sreg * 4);   // ~9.8 MB
    u16*   W1t    = (u16*)alloc((size_t)IN * HID * 2);     // [128][256] bf16
    u16*   W2t    = (u16*)alloc((size_t)HID * HID1 * 2);   // [64][128] bf16
    // shared region: bp1+bp2 (CSR build) -> g1 (gemm1/agg128) -> h2 (agg64/out); sequential
    size_t bp1Bytes = (size_t)NB1 * bcap1 * 8;
    size_t bp2Bytes = (size_t)NB2 * bcap2 * 8;
    size_t sharedBytes = bp1Bytes + bp2Bytes;              // ~31 MB
    size_t gBytes = (size_t)(N + 1) * HID * 2;             // 25.6 MB (+ sentinel row)
    if (gBytes > sharedBytes) sharedBytes = gBytes;
    char*  shared = (char*)alloc(sharedBytes);
    int2*  bp1    = (int2*)shared;
    int2*  bp2    = (int2*)(shared + bp1Bytes);
    u16*   g1     = (u16*)shared;                          // bf16 [N+1][128]
    u16*   h2     = (u16*)shared;                          // bf16 [N][64]
    u16*   h1     = (u16*)alloc((size_t)N * HID * 2);      // bf16 [N][128]
    u16*   g2     = (u16*)alloc((size_t)(N + 1) * HID1 * 2); // bf16 [N+1][64]

    // ---- CSR build: contention-free chunked routing, padded rows ----
    hipMemsetAsync(atom, 0, (NB1 + NB2) * 4, stream);
    const int nchunk1 = (E + CHUNK - 1) / CHUNK;           // 196
    route1<<<nchunk1, 256, 0, stream>>>(src, dst, E, R1, bcur1, bp1, bcap1);
    const int nchunk2 = (bcap1 + CHUNK - 1) / CHUNK;       // 14
    route2<<<NB1 * nchunk2, 256, 0, stream>>>(bp1, bcur1, bcap1, R1, R2, bcur2, bp2, bcap2);
    build_csr<<<NB2, 256, 0, stream>>>(bp2, bcur2, bcap2, sreg, R2, N, rs, re, dinv, srcids);
    zero_pad<<<1, 64, 0, stream>>>((u32*)g1, (u32*)g2, N);

    // weights -> bf16 transposed
    conv_w2<<<(IN * HID + HID * HID1 + 255) / 256, 256, 0, stream>>>(
        W1, W1t, IN, HID, W2, W2t, HID, HID1);

    const int gblocks = (N + 127) / 128;
    // layer 1: g1 = bf16((x @ W1) * dinv); h1 = bf16(relu(agg(g1)*dinv + b1))
    gemm_mfma<256, 128, 4, 4, 2, 2, false><<<gblocks, 256, 0, stream>>>(x, W1t, dinv, g1, N);
    agg128<<<(N + 15) / 16, 256, 0, stream>>>((const uint4*)g1, (const float4*)b1,
                                              rs, re, srcids, dinv, (uint4*)h1, N);

    // layer 2: g2 = bf16((h1 @ W2) * dinv); h2 = bf16(agg(g2)*dinv + b2)
    gemm_mfma<128, 64, 2, 4, 4, 1, true><<<gblocks, 256, 0, stream>>>(h1, W2t, dinv, g2, N);
    agg64<<<(N + 15) / 16, 256, 0, stream>>>((const uint2*)g2, (const float4*)b2,
                                             rs, re, srcids, dinv, (uint2*)h2, N);

    // output head + log_softmax (h2 bf16)
    out_kernel<<<(N + 255) / 256, 256, 0, stream>>>((const uint4*)h2, Wo, bo, out, N);
    (void)ws_size; (void)n_in; (void)out_size; (void)HID1;
}

// Round 11
// 215.656 us; speedup vs baseline: 2.0640x; 1.1878x over previous
//
#include <hip/hip_runtime.h>
#include <hip/hip_bf16.h>

typedef unsigned short u16;
typedef unsigned int u32;
typedef __attribute__((ext_vector_type(8))) short bf16x8;   // 8 bf16 (4 VGPRs)
typedef __attribute__((ext_vector_type(4))) float f32x4;
typedef __attribute__((ext_vector_type(4))) u16 u16x4;

__device__ __forceinline__ u16 f2bf(float f) {
    union { float f; u32 u; } v; v.f = f;
    u32 r = v.u + 0x7FFF + ((v.u >> 16) & 1);   // RNE
    return (u16)(r >> 16);
}
__device__ __forceinline__ float bf_lo(u32 u) {
    union { u32 u; float f; } v; v.u = u << 16; return v.f;
}
__device__ __forceinline__ float bf_hi(u32 u) {
    union { u32 u; float f; } v; v.u = u & 0xFFFF0000u; return v.f;
}
__device__ __forceinline__ u32 pack2(float a, float b) {
    return (u32)f2bf(a) | ((u32)f2bf(b) << 16);
}

#define NB2 256    // final buckets (single-level routing)
#define CHUNK 8192 // edges per routing block (32 per thread)

// ---------------- single-pass routing: edges -> 256 dst-range buckets ----------------
// LDS histogram (low-contention 256-bin atomics), ONE reservation atomic per bucket
// per block (196 per address total), LDS-cursor scatter. No per-edge global atomics.
__launch_bounds__(256)
__global__ void route(const int* __restrict__ src, const int* __restrict__ dst, int E, int R2,
                      int* __restrict__ bcur, int2* __restrict__ bp, int bcap) {
    __shared__ int cnt[NB2];
    __shared__ int cur[NB2];
    const int tid = threadIdx.x;
    const int base = blockIdx.x * CHUNK;
    cnt[tid] = 0;
    __syncthreads();
#pragma unroll 4
    for (int i = 0; i < CHUNK / 256; i++) {
        int e = base + i * 256 + tid;
        if (e < E) atomicAdd(&cnt[dst[e] / R2], 1);
    }
    __syncthreads();
    {
        int c = cnt[tid];
        cur[tid] = c ? atomicAdd(&bcur[tid], c) : 0;
    }
    __syncthreads();
#pragma unroll 4
    for (int i = 0; i < CHUNK / 256; i++) {
        int e = base + i * 256 + tid;
        if (e < E) {
            int d = dst[e], s = src[e];
            int b = d / R2;
            int pos = atomicAdd(&cur[b], 1);
            if (pos < bcap) bp[(size_t)b * bcap + pos] = (int2){s, d};
        }
    }
}

// ---------------- per-bucket CSR build with 4-aligned padded rows ----------------
// rs/re per node; segments padded to x4 with sentinel src = N (zero row); fixed
// per-bucket srcids regions (b * sreg, sreg % 4 == 0 so every segment is int4-aligned)
__launch_bounds__(256)
__global__ void build_csr(const int2* __restrict__ bp2, const int* __restrict__ bcnt2, int bcap2,
                          int sreg, int R2, int N,
                          int* __restrict__ rs, int* __restrict__ re,
                          float* __restrict__ dinv, int* __restrict__ srcids) {
    __shared__ int bins[1024];       // R2 <= 1024
    __shared__ int tsum[256];
    const int b = blockIdx.x;
    const int tid = threadIdx.x;
    const int lo = b * R2;
    int hi = lo + R2; if (hi > N) hi = N;
    const int nb = hi - lo;
    if (nb <= 0) return;
    int cnt = bcnt2[b];
    if (cnt > bcap2) cnt = bcap2;
    const int2* mine = bp2 + (size_t)b * bcap2;

    for (int i = tid; i < nb; i += 256) bins[i] = 0;
    __syncthreads();
    for (int i = tid; i < cnt; i += 256) {
        int2 p = mine[i];
        atomicAdd(&bins[p.y - lo], 1);
    }
    __syncthreads();

    const int base4 = tid * 4;
    int creal[4], cpad[4], ex[4];
    int run = 0;
#pragma unroll
    for (int k = 0; k < 4; k++) {
        int idx = base4 + k;
        creal[k] = 0; cpad[k] = 0; ex[k] = 0;
        if (idx < nb) {
            int c = bins[idx];
            creal[k] = c;
            cpad[k] = (c + 3) & ~3;
            dinv[lo + idx] = rsqrtf((float)c + 1.0f);
            ex[k] = run;
            run += cpad[k];
        }
    }
    tsum[tid] = run;
    __syncthreads();
    for (int off = 1; off < 256; off <<= 1) {
        int u = (tid >= off) ? tsum[tid - off] : 0;
        __syncthreads();
        tsum[tid] += u;
        __syncthreads();
    }
    const int toff = ((tid > 0) ? tsum[tid - 1] : 0) + b * sreg;
    __syncthreads();
#pragma unroll
    for (int k = 0; k < 4; k++) {
        int idx = base4 + k;
        if (idx < nb) {
            int st = toff + ex[k];
            bins[idx] = st;                    // absolute fill cursor
            rs[lo + idx] = st;
            re[lo + idx] = st + cpad[k];
            for (int q = creal[k]; q < cpad[k]; q++) srcids[st + q] = N;  // sentinel
        }
    }
    __syncthreads();
    for (int i = tid; i < cnt; i += 256) {
        int2 p = mine[i];
        int pos = atomicAdd(&bins[p.y - lo], 1);
        srcids[pos] = p.x;
    }
}

// ---------------- zero sentinel rows (row N of g1 and g2) ----------------
__global__ void zero_pad(u32* __restrict__ g1, u32* __restrict__ g2, int N) {
    int t = threadIdx.x;
    if (t < 64) g1[(size_t)N * 64 + t] = 0;
    if (t < 32) g2[(size_t)N * 32 + t] = 0;
}

// ---------------- weight transpose+convert (both layers in one kernel) ----------------
__global__ void conv_w2(const float* __restrict__ W1, u16* __restrict__ B1, int K1, int N1,
                        const float* __restrict__ W2, u16* __restrict__ B2, int K2, int N2) {
    int i = blockIdx.x * 256 + threadIdx.x;
    int sz1 = K1 * N1;
    if (i < sz1) {
        int n = i / K1, k = i - n * K1;
        B1[i] = f2bf(W1[(size_t)k * N1 + n]);
    } else if (i - sz1 < K2 * N2) {
        int j = i - sz1;
        int n = j / K2, k = j - n * K2;
        B2[j] = f2bf(W2[(size_t)k * N2 + n]);
    }
}

// ---------------- MFMA bf16 GEMM: G[m][n] = bf16( (A @ Bt^T)[m][n] * dinv[m] ) ----------------
template <int K, int BN, int IFR, int JFR, int WM, int WN, bool ABF16>
__launch_bounds__(256)
__global__ void gemm_mfma(const void* __restrict__ Av, const u16* __restrict__ Bt,
                          const float* __restrict__ dinv, u16* __restrict__ G, int M) {
    constexpr int BM = 128, BK = 32;
    __shared__ u16 As[BM][BK];   // 64 B rows -> conflict-free b128 frag reads
    __shared__ u16 Bs[BN][BK];
    const int tid = threadIdx.x;
    const int lane = tid & 63, wave = tid >> 6;
    const int r = lane & 15, g = lane >> 4;
    const int wm = wave % WM, wn = wave / WM;
    const int m0 = blockIdx.x * BM;

    f32x4 acc[IFR][JFR];
#pragma unroll
    for (int i = 0; i < IFR; i++)
#pragma unroll
        for (int j = 0; j < JFR; j++) acc[i][j] = (f32x4){0.f, 0.f, 0.f, 0.f};

    for (int k0 = 0; k0 < K; k0 += BK) {
#pragma unroll
        for (int p = 0; p < 4; p++) {
            int q = tid + p * 256;
            int row = q >> 3, kq = (q & 7) << 2;
            int gr = m0 + row; if (gr >= M) gr = M - 1;   // clamp; stores guarded
            if constexpr (ABF16) {
                const u16* A = (const u16*)Av;
                *(u16x4*)&As[row][kq] = *(const u16x4*)(A + (size_t)gr * K + k0 + kq);
            } else {
                const float* A = (const float*)Av;
                float4 a = *(const float4*)(A + (size_t)gr * K + k0 + kq);
                u16x4 v = { f2bf(a.x), f2bf(a.y), f2bf(a.z), f2bf(a.w) };
                *(u16x4*)&As[row][kq] = v;
            }
        }
#pragma unroll
        for (int p = 0; p < BN / 32; p++) {
            int q = tid + p * 256;
            int row = q >> 3, kq = (q & 7) << 2;
            *(u16x4*)&Bs[row][kq] = *(const u16x4*)(Bt + (size_t)row * K + k0 + kq);
        }
        __syncthreads();

        bf16x8 af[IFR], bfr[JFR];
#pragma unroll
        for (int i = 0; i < IFR; i++)
            af[i] = *(const bf16x8*)&As[wm * (IFR * 16) + i * 16 + r][g * 8];
#pragma unroll
        for (int j = 0; j < JFR; j++)
            bfr[j] = *(const bf16x8*)&Bs[wn * (JFR * 16) + j * 16 + r][g * 8];
#pragma unroll
        for (int i = 0; i < IFR; i++)
#pragma unroll
            for (int j = 0; j < JFR; j++)
                acc[i][j] = __builtin_amdgcn_mfma_f32_16x16x32_bf16(af[i], bfr[j], acc[i][j], 0, 0, 0);
        __syncthreads();
    }

    // C/D layout: col=lane&15, row=(lane>>4)*4+reg
#pragma unroll
    for (int i = 0; i < IFR; i++) {
#pragma unroll
        for (int t = 0; t < 4; t++) {
            int row = m0 + wm * (IFR * 16) + i * 16 + g * 4 + t;
            if (row < M) {
                float dn = dinv[row];
#pragma unroll
                for (int j = 0; j < JFR; j++) {
                    int col = wn * (JFR * 16) + j * 16 + r;
                    G[(size_t)row * BN + col] = f2bf(acc[i][j][t] * dn);
                }
            }
        }
    }
}

#define ACC8(v) { a0 += bf_lo(v.x); a1 += bf_hi(v.x); a2 += bf_lo(v.y); a3 += bf_hi(v.y); \
                  a4 += bf_lo(v.z); a5 += bf_hi(v.z); a6 += bf_lo(v.w); a7 += bf_hi(v.w); }

// ---------------- agg F=128: 16-lane quarter per node; pipelined int4 index loads ----------------
__launch_bounds__(256)
__global__ void agg128(const uint4* __restrict__ g1, const float4* __restrict__ bias,
                       const int* __restrict__ rs, const int* __restrict__ re,
                       const int* __restrict__ srcids, const float* __restrict__ dinv,
                       uint4* __restrict__ h1, int n) {
    const int tq = threadIdx.x >> 4;       // quarter [0,16)
    const int c  = threadIdx.x & 15;       // 16B slice
    const int node = blockIdx.x * 16 + tq;
    if (node >= n) return;
    const float dn = dinv[node];
    uint4 sv = g1[(size_t)node * 16 + c];
    float a0 = bf_lo(sv.x), a1 = bf_hi(sv.x), a2 = bf_lo(sv.y), a3 = bf_hi(sv.y);
    float a4 = bf_lo(sv.z), a5 = bf_hi(sv.z), a6 = bf_lo(sv.w), a7 = bf_hi(sv.w);

    int j = rs[node] >> 2;                 // int4-granular (segments 4-aligned+padded)
    const int jend = re[node] >> 2;
    const int4* ip = (const int4*)srcids;
    if (j < jend) {
        int4 idx = ip[j];
        for (++j; j < jend; ++j) {
            uint4 v0 = g1[(size_t)idx.x * 16 + c];
            uint4 v1 = g1[(size_t)idx.y * 16 + c];
            uint4 v2 = g1[(size_t)idx.z * 16 + c];
            uint4 v3 = g1[(size_t)idx.w * 16 + c];
            int4 nxt = ip[j];              // prefetch next indices under the gathers
            ACC8(v0); ACC8(v1); ACC8(v2); ACC8(v3);
            idx = nxt;
        }
        uint4 v0 = g1[(size_t)idx.x * 16 + c];
        uint4 v1 = g1[(size_t)idx.y * 16 + c];
        uint4 v2 = g1[(size_t)idx.z * 16 + c];
        uint4 v3 = g1[(size_t)idx.w * 16 + c];
        ACC8(v0); ACC8(v1); ACC8(v2); ACC8(v3);
    }

    float4 b0 = bias[c * 2], b1v = bias[c * 2 + 1];
    uint4 w;
    w.x = pack2(fmaxf(a0 * dn + b0.x, 0.f), fmaxf(a1 * dn + b0.y, 0.f));
    w.y = pack2(fmaxf(a2 * dn + b0.z, 0.f), fmaxf(a3 * dn + b0.w, 0.f));
    w.z = pack2(fmaxf(a4 * dn + b1v.x, 0.f), fmaxf(a5 * dn + b1v.y, 0.f));
    w.w = pack2(fmaxf(a6 * dn + b1v.z, 0.f), fmaxf(a7 * dn + b1v.w, 0.f));
    h1[(size_t)node * 16 + c] = w;
}

// ---------------- fused agg F=64 + head + log_softmax ----------------
// quarter-per-node gather (as before); h2 row staged in LDS (fp32, padded rows);
// lane-parallel logits (16 lanes x 2-3 each); short intra-quarter shfl reductions.
__launch_bounds__(256)
__global__ void agg64out(const uint2* __restrict__ g2, const float4* __restrict__ bias,
                         const int* __restrict__ rs, const int* __restrict__ re,
                         const int* __restrict__ srcids, const float* __restrict__ dinv,
                         const float* __restrict__ Wo, const float* __restrict__ bo,
                         float* __restrict__ out, int n) {
    __shared__ float Ws[64 * 40];
    __shared__ float bs[40];
    __shared__ float h2s[16][68];          // row stride 68 -> quarters hit distinct banks
    for (int i = threadIdx.x; i < 64 * 40; i += 256) Ws[i] = Wo[i];
    if (threadIdx.x < 40) bs[threadIdx.x] = bo[threadIdx.x];

    const int tq = threadIdx.x >> 4;
    const int c  = threadIdx.x & 15;
    const int node = blockIdx.x * 16 + tq;
    if (node < n) {
        const float dn = dinv[node];
        uint2 sv = g2[(size_t)node * 16 + c];
        float a0 = bf_lo(sv.x), a1 = bf_hi(sv.x), a2 = bf_lo(sv.y), a3 = bf_hi(sv.y);
        int j = rs[node] >> 2;
        const int jend = re[node] >> 2;
        const int4* ip = (const int4*)srcids;
        if (j < jend) {
            int4 idx = ip[j];
            for (++j; j < jend; ++j) {
                uint2 v0 = g2[(size_t)idx.x * 16 + c];
                uint2 v1 = g2[(size_t)idx.y * 16 + c];
                uint2 v2 = g2[(size_t)idx.z * 16 + c];
                uint2 v3 = g2[(size_t)idx.w * 16 + c];
                int4 nxt = ip[j];
                a0 += (bf_lo(v0.x) + bf_lo(v1.x)) + (bf_lo(v2.x) + bf_lo(v3.x));
                a1 += (bf_hi(v0.x) + bf_hi(v1.x)) + (bf_hi(v2.x) + bf_hi(v3.x));
                a2 += (bf_lo(v0.y) + bf_lo(v1.y)) + (bf_lo(v2.y) + bf_lo(v3.y));
                a3 += (bf_hi(v0.y) + bf_hi(v1.y)) + (bf_hi(v2.y) + bf_hi(v3.y));
                idx = nxt;
            }
            uint2 v0 = g2[(size_t)idx.x * 16 + c];
            uint2 v1 = g2[(size_t)idx.y * 16 + c];
            uint2 v2 = g2[(size_t)idx.z * 16 + c];
            uint2 v3 = g2[(size_t)idx.w * 16 + c];
            a0 += (bf_lo(v0.x) + bf_lo(v1.x)) + (bf_lo(v2.x) + bf_lo(v3.x));
            a1 += (bf_hi(v0.x) + bf_hi(v1.x)) + (bf_hi(v2.x) + bf_hi(v3.x));
            a2 += (bf_lo(v0.y) + bf_lo(v1.y)) + (bf_lo(v2.y) + bf_lo(v3.y));
            a3 += (bf_hi(v0.y) + bf_hi(v1.y)) + (bf_hi(v2.y) + bf_hi(v3.y));
        }
        float4 bb = bias[c];
        float4 hv = { a0 * dn + bb.x, a1 * dn + bb.y, a2 * dn + bb.z, a3 * dn + bb.w };
        *(float4*)&h2s[tq][c * 4] = hv;
    }
    __syncthreads();

    if (node < n) {
        const int j2 = (c < 8) ? (c + 32) : 39;        // duplicate for c>=8, discarded
        float l0 = bs[c], l1 = bs[c + 16], l2 = bs[j2];
#pragma unroll 8
        for (int k = 0; k < 64; k++) {
            float hk = h2s[tq][k];
            l0 = fmaf(hk, Ws[k * 40 + c], l0);
            l1 = fmaf(hk, Ws[k * 40 + c + 16], l1);
            l2 = fmaf(hk, Ws[k * 40 + j2], l2);
        }
        float m = fmaxf(fmaxf(l0, l1), (c < 8) ? l2 : -3.0e38f);
#pragma unroll
        for (int o = 1; o < 16; o <<= 1) m = fmaxf(m, __shfl_xor(m, o));
        float s = expf(l0 - m) + expf(l1 - m) + ((c < 8) ? expf(l2 - m) : 0.f);
#pragma unroll
        for (int o = 1; o < 16; o <<= 1) s += __shfl_xor(s, o);
        float lse = m + logf(s);
        float* op = out + (size_t)node * 40;
        op[c] = l0 - lse;
        op[c + 16] = l1 - lse;
        if (c < 8) op[c + 32] = l2 - lse;
    }
}

extern "C" void kernel_launch(void* const* d_in, const int* in_sizes, int n_in,
                              void* d_out, int out_size, void* d_ws, size_t ws_size,
                              hipStream_t stream) {
    const float* x  = (const float*)d_in[0];
    const int*   ei = (const int*)d_in[1];
    const float* W1 = (const float*)d_in[2];
    const float* b1 = (const float*)d_in[3];
    const float* W2 = (const float*)d_in[4];
    const float* b2 = (const float*)d_in[5];
    const float* Wo = (const float*)d_in[6];
    const float* bo = (const float*)d_in[7];
    float* out = (float*)d_out;

    const int HID  = in_sizes[3];           // 128
    const int IN   = in_sizes[2] / HID;     // 256
    const int HID1 = in_sizes[5];           // 64
    const int N = in_sizes[0] / IN;         // 100000
    const int E = in_sizes[1] / 2;          // 1600000
    const int* src = ei;
    const int* dst = ei + E;

    const int R2 = (N + NB2 - 1) / NB2;     // 391
    const int bcap2 = E / NB2 + 2048;       // 8298 (~26 sigma)
    const int sreg  = (bcap2 + 3 * R2 + 32 + 3) & ~3;   // region stride, %4==0 (alignment invariant)

    char* ws = (char*)d_ws;
    size_t off = 0;
    auto alloc = [&](size_t bytes) -> void* {
        void* p = ws + off;
        off += (bytes + 255) / 256 * 256;
        return p;
    };
    float* dinv   = (float*)alloc((size_t)N * 4);
    int*   rs     = (int*)alloc((size_t)N * 4);
    int*   re     = (int*)alloc((size_t)N * 4);
    int*   bcur   = (int*)alloc(NB2 * 4);
    int*   srcids = (int*)alloc((size_t)NB2 * sreg * 4);   // ~9.7 MB
    u16*   W1t    = (u16*)alloc((size_t)IN * HID * 2);     // [128][256] bf16
    u16*   W2t    = (u16*)alloc((size_t)HID * HID1 * 2);   // [64][128] bf16
    // shared region: bp2 (CSR build) -> g1 (gemm1/agg128); strictly sequential
    size_t bp2Bytes = (size_t)NB2 * bcap2 * 8;             // ~17 MB
    size_t gBytes = (size_t)(N + 1) * HID * 2;             // 25.6 MB (+ sentinel row)
    size_t sharedBytes = (gBytes > bp2Bytes) ? gBytes : bp2Bytes;
    char*  shared = (char*)alloc(sharedBytes);
    int2*  bp2    = (int2*)shared;
    u16*   g1     = (u16*)shared;                          // bf16 [N+1][128]
    u16*   h1     = (u16*)alloc((size_t)N * HID * 2);      // bf16 [N][128]
    u16*   g2     = (u16*)alloc((size_t)(N + 1) * HID1 * 2); // bf16 [N+1][64]

    // ---- CSR build: single-pass 256-way routing, padded rows ----
    hipMemsetAsync(bcur, 0, NB2 * 4, stream);
    const int nchunk = (E + CHUNK - 1) / CHUNK;            // 196
    route<<<nchunk, 256, 0, stream>>>(src, dst, E, R2, bcur, bp2, bcap2);
    build_csr<<<NB2, 256, 0, stream>>>(bp2, bcur, bcap2, sreg, R2, N, rs, re, dinv, srcids);
    zero_pad<<<1, 64, 0, stream>>>((u32*)g1, (u32*)g2, N);

    // weights -> bf16 transposed
    conv_w2<<<(IN * HID + HID * HID1 + 255) / 256, 256, 0, stream>>>(
        W1, W1t, IN, HID, W2, W2t, HID, HID1);

    const int gblocks = (N + 127) / 128;
    // layer 1: g1 = bf16((x @ W1) * dinv); h1 = bf16(relu(agg(g1)*dinv + b1))
    gemm_mfma<256, 128, 4, 4, 2, 2, false><<<gblocks, 256, 0, stream>>>(x, W1t, dinv, g1, N);
    agg128<<<(N + 15) / 16, 256, 0, stream>>>((const uint4*)g1, (const float4*)b1,
                                              rs, re, srcids, dinv, (uint4*)h1, N);

    // layer 2: g2 = bf16((h1 @ W2) * dinv); out = log_softmax((agg(g2)*dinv + b2) @ Wo + bo)
    gemm_mfma<128, 64, 2, 4, 4, 1, true><<<gblocks, 256, 0, stream>>>(h1, W2t, dinv, g2, N);
    agg64out<<<(N + 15) / 16, 256, 0, stream>>>((const uint2*)g2, (const float4*)b2,
                                                rs, re, srcids, dinv, Wo, bo, out, N);

    (void)ws_size; (void)n_in; (void)out_size; (void)HID1;
}

// Round 12
// 214.161 us; speedup vs baseline: 2.0784x; 1.0070x over previous
//
#include <hip/hip_runtime.h>
#include <hip/hip_bf16.h>

typedef unsigned short u16;
typedef unsigned int u32;
typedef __attribute__((ext_vector_type(8))) short bf16x8;   // 8 bf16 (4 VGPRs)
typedef __attribute__((ext_vector_type(4))) float f32x4;
typedef __attribute__((ext_vector_type(4))) u16 u16x4;

// hardware RNE cvt (compiler emits v_cvt_pk_bf16_f32 for adjacent pairs — m240)
__device__ __forceinline__ u16 f2bf(float f) {
    __hip_bfloat16 h = __float2bfloat16(f);
    return *reinterpret_cast<u16*>(&h);
}
__device__ __forceinline__ float bf_lo(u32 u) {
    union { u32 u; float f; } v; v.u = u << 16; return v.f;
}
__device__ __forceinline__ float bf_hi(u32 u) {
    union { u32 u; float f; } v; v.u = u & 0xFFFF0000u; return v.f;
}
__device__ __forceinline__ u32 pack2(float a, float b) {
    return (u32)f2bf(a) | ((u32)f2bf(b) << 16);
}

#define NB2 256    // final buckets (single-level routing)
#define CHUNK 8192 // edges per routing block (32 per thread)

// ---------------- single-pass routing: edges -> 256 dst-range buckets ----------------
__launch_bounds__(256)
__global__ void route(const int* __restrict__ src, const int* __restrict__ dst, int E, int R2,
                      int* __restrict__ bcur, int2* __restrict__ bp, int bcap) {
    __shared__ int cnt[NB2];
    __shared__ int cur[NB2];
    const int tid = threadIdx.x;
    const int base = blockIdx.x * CHUNK;
    cnt[tid] = 0;
    __syncthreads();
#pragma unroll 4
    for (int i = 0; i < CHUNK / 256; i++) {
        int e = base + i * 256 + tid;
        if (e < E) atomicAdd(&cnt[dst[e] / R2], 1);
    }
    __syncthreads();
    {
        int c = cnt[tid];
        cur[tid] = c ? atomicAdd(&bcur[tid], c) : 0;
    }
    __syncthreads();
#pragma unroll 4
    for (int i = 0; i < CHUNK / 256; i++) {
        int e = base + i * 256 + tid;
        if (e < E) {
            int d = dst[e], s = src[e];
            int b = d / R2;
            int pos = atomicAdd(&cur[b], 1);
            if (pos < bcap) bp[(size_t)b * bcap + pos] = (int2){s, d};
        }
    }
}

// ---------------- per-bucket CSR build with 4-aligned padded rows ----------------
__launch_bounds__(256)
__global__ void build_csr(const int2* __restrict__ bp2, const int* __restrict__ bcnt2, int bcap2,
                          int sreg, int R2, int N,
                          int* __restrict__ rs, int* __restrict__ re,
                          float* __restrict__ dinv, int* __restrict__ srcids) {
    __shared__ int bins[1024];       // R2 <= 1024
    __shared__ int tsum[256];
    const int b = blockIdx.x;
    const int tid = threadIdx.x;
    const int lo = b * R2;
    int hi = lo + R2; if (hi > N) hi = N;
    const int nb = hi - lo;
    if (nb <= 0) return;
    int cnt = bcnt2[b];
    if (cnt > bcap2) cnt = bcap2;
    const int2* mine = bp2 + (size_t)b * bcap2;

    for (int i = tid; i < nb; i += 256) bins[i] = 0;
    __syncthreads();
    for (int i = tid; i < cnt; i += 256) {
        int2 p = mine[i];
        atomicAdd(&bins[p.y - lo], 1);
    }
    __syncthreads();

    const int base4 = tid * 4;
    int creal[4], cpad[4], ex[4];
    int run = 0;
#pragma unroll
    for (int k = 0; k < 4; k++) {
        int idx = base4 + k;
        creal[k] = 0; cpad[k] = 0; ex[k] = 0;
        if (idx < nb) {
            int c = bins[idx];
            creal[k] = c;
            cpad[k] = (c + 3) & ~3;
            dinv[lo + idx] = rsqrtf((float)c + 1.0f);
            ex[k] = run;
            run += cpad[k];
        }
    }
    tsum[tid] = run;
    __syncthreads();
    for (int off = 1; off < 256; off <<= 1) {
        int u = (tid >= off) ? tsum[tid - off] : 0;
        __syncthreads();
        tsum[tid] += u;
        __syncthreads();
    }
    const int toff = ((tid > 0) ? tsum[tid - 1] : 0) + b * sreg;
    __syncthreads();
#pragma unroll
    for (int k = 0; k < 4; k++) {
        int idx = base4 + k;
        if (idx < nb) {
            int st = toff + ex[k];
            bins[idx] = st;                    // absolute fill cursor
            rs[lo + idx] = st;
            re[lo + idx] = st + cpad[k];
            for (int q = creal[k]; q < cpad[k]; q++) srcids[st + q] = N;  // sentinel
        }
    }
    __syncthreads();
    for (int i = tid; i < cnt; i += 256) {
        int2 p = mine[i];
        int pos = atomicAdd(&bins[p.y - lo], 1);
        srcids[pos] = p.x;
    }
}

// ---------------- zero sentinel rows (row N of g1 and g2) ----------------
__global__ void zero_pad(u32* __restrict__ g1, u32* __restrict__ g2, int N) {
    int t = threadIdx.x;
    if (t < 64) g1[(size_t)N * 64 + t] = 0;
    if (t < 32) g2[(size_t)N * 32 + t] = 0;
}

// ---------------- weight transpose+convert (both layers in one kernel) ----------------
__global__ void conv_w2(const float* __restrict__ W1, u16* __restrict__ B1, int K1, int N1,
                        const float* __restrict__ W2, u16* __restrict__ B2, int K2, int N2) {
    int i = blockIdx.x * 256 + threadIdx.x;
    int sz1 = K1 * N1;
    if (i < sz1) {
        int n = i / K1, k = i - n * K1;
        B1[i] = f2bf(W1[(size_t)k * N1 + n]);
    } else if (i - sz1 < K2 * N2) {
        int j = i - sz1;
        int n = j / K2, k = j - n * K2;
        B2[j] = f2bf(W2[(size_t)k * N2 + n]);
    }
}

// ---------------- MFMA bf16 GEMM: G[m][n] = bf16( (A @ Bt^T)[m][n] * dinv[m] ) ----------------
// LDS rows padded to 40 u16 (80 B): r*20 mod 32 spreads 16 rows over 8 bank-quads
// -> 2-way (free) instead of 8-way conflict on ds_read_b128 frag reads; 80%16==0
// keeps 16B row alignment.
template <int K, int BN, int IFR, int JFR, int WM, int WN, bool ABF16>
__launch_bounds__(256)
__global__ void gemm_mfma(const void* __restrict__ Av, const u16* __restrict__ Bt,
                          const float* __restrict__ dinv, u16* __restrict__ G, int M) {
    constexpr int BM = 128, BK = 32, BKP = 40;
    __shared__ u16 As[BM][BKP];
    __shared__ u16 Bs[BN][BKP];
    const int tid = threadIdx.x;
    const int lane = tid & 63, wave = tid >> 6;
    const int r = lane & 15, g = lane >> 4;
    const int wm = wave % WM, wn = wave / WM;
    const int m0 = blockIdx.x * BM;

    f32x4 acc[IFR][JFR];
#pragma unroll
    for (int i = 0; i < IFR; i++)
#pragma unroll
        for (int j = 0; j < JFR; j++) acc[i][j] = (f32x4){0.f, 0.f, 0.f, 0.f};

    for (int k0 = 0; k0 < K; k0 += BK) {
#pragma unroll
        for (int p = 0; p < 4; p++) {
            int q = tid + p * 256;
            int row = q >> 3, kq = (q & 7) << 2;
            int gr = m0 + row; if (gr >= M) gr = M - 1;   // clamp; stores guarded
            if constexpr (ABF16) {
                const u16* A = (const u16*)Av;
                *(u16x4*)&As[row][kq] = *(const u16x4*)(A + (size_t)gr * K + k0 + kq);
            } else {
                const float* A = (const float*)Av;
                float4 a = *(const float4*)(A + (size_t)gr * K + k0 + kq);
                u16x4 v = { f2bf(a.x), f2bf(a.y), f2bf(a.z), f2bf(a.w) };
                *(u16x4*)&As[row][kq] = v;
            }
        }
#pragma unroll
        for (int p = 0; p < BN / 32; p++) {
            int q = tid + p * 256;
            int row = q >> 3, kq = (q & 7) << 2;
            *(u16x4*)&Bs[row][kq] = *(const u16x4*)(Bt + (size_t)row * K + k0 + kq);
        }
        __syncthreads();

        bf16x8 af[IFR], bfr[JFR];
#pragma unroll
        for (int i = 0; i < IFR; i++)
            af[i] = *(const bf16x8*)&As[wm * (IFR * 16) + i * 16 + r][g * 8];
#pragma unroll
        for (int j = 0; j < JFR; j++)
            bfr[j] = *(const bf16x8*)&Bs[wn * (JFR * 16) + j * 16 + r][g * 8];
#pragma unroll
        for (int i = 0; i < IFR; i++)
#pragma unroll
            for (int j = 0; j < JFR; j++)
                acc[i][j] = __builtin_amdgcn_mfma_f32_16x16x32_bf16(af[i], bfr[j], acc[i][j], 0, 0, 0);
        __syncthreads();
    }

    // C/D layout: col=lane&15, row=(lane>>4)*4+reg
#pragma unroll
    for (int i = 0; i < IFR; i++) {
#pragma unroll
        for (int t = 0; t < 4; t++) {
            int row = m0 + wm * (IFR * 16) + i * 16 + g * 4 + t;
            if (row < M) {
                float dn = dinv[row];
#pragma unroll
                for (int j = 0; j < JFR; j++) {
                    int col = wn * (JFR * 16) + j * 16 + r;
                    G[(size_t)row * BN + col] = f2bf(acc[i][j][t] * dn);
                }
            }
        }
    }
}

#define ACC8(v) { a0 += bf_lo(v.x); a1 += bf_hi(v.x); a2 += bf_lo(v.y); a3 += bf_hi(v.y); \
                  a4 += bf_lo(v.z); a5 += bf_hi(v.z); a6 += bf_lo(v.w); a7 += bf_hi(v.w); }

// ---------------- agg F=128: 16-lane quarter per node; pipelined int4 index loads ----------------
__launch_bounds__(256)
__global__ void agg128(const uint4* __restrict__ g1, const float4* __restrict__ bias,
                       const int* __restrict__ rs, const int* __restrict__ re,
                       const int* __restrict__ srcids, const float* __restrict__ dinv,
                       uint4* __restrict__ h1, int n) {
    const int tq = threadIdx.x >> 4;       // quarter [0,16)
    const int c  = threadIdx.x & 15;       // 16B slice
    const int node = blockIdx.x * 16 + tq;
    if (node >= n) return;
    const float dn = dinv[node];
    uint4 sv = g1[(size_t)node * 16 + c];
    float a0 = bf_lo(sv.x), a1 = bf_hi(sv.x), a2 = bf_lo(sv.y), a3 = bf_hi(sv.y);
    float a4 = bf_lo(sv.z), a5 = bf_hi(sv.z), a6 = bf_lo(sv.w), a7 = bf_hi(sv.w);

    int j = rs[node] >> 2;                 // int4-granular (segments 4-aligned+padded)
    const int jend = re[node] >> 2;
    const int4* ip = (const int4*)srcids;
    if (j < jend) {
        int4 idx = ip[j];
        for (++j; j < jend; ++j) {
            uint4 v0 = g1[(size_t)idx.x * 16 + c];
            uint4 v1 = g1[(size_t)idx.y * 16 + c];
            uint4 v2 = g1[(size_t)idx.z * 16 + c];
            uint4 v3 = g1[(size_t)idx.w * 16 + c];
            int4 nxt = ip[j];              // prefetch next indices under the gathers
            ACC8(v0); ACC8(v1); ACC8(v2); ACC8(v3);
            idx = nxt;
        }
        uint4 v0 = g1[(size_t)idx.x * 16 + c];
        uint4 v1 = g1[(size_t)idx.y * 16 + c];
        uint4 v2 = g1[(size_t)idx.z * 16 + c];
        uint4 v3 = g1[(size_t)idx.w * 16 + c];
        ACC8(v0); ACC8(v1); ACC8(v2); ACC8(v3);
    }

    float4 b0 = bias[c * 2], b1v = bias[c * 2 + 1];
    uint4 w;
    w.x = pack2(fmaxf(a0 * dn + b0.x, 0.f), fmaxf(a1 * dn + b0.y, 0.f));
    w.y = pack2(fmaxf(a2 * dn + b0.z, 0.f), fmaxf(a3 * dn + b0.w, 0.f));
    w.z = pack2(fmaxf(a4 * dn + b1v.x, 0.f), fmaxf(a5 * dn + b1v.y, 0.f));
    w.w = pack2(fmaxf(a6 * dn + b1v.z, 0.f), fmaxf(a7 * dn + b1v.w, 0.f));
    h1[(size_t)node * 16 + c] = w;
}

// ---------------- fused agg F=64 + head + log_softmax ----------------
__launch_bounds__(256)
__global__ void agg64out(const uint2* __restrict__ g2, const float4* __restrict__ bias,
                         const int* __restrict__ rs, const int* __restrict__ re,
                         const int* __restrict__ srcids, const float* __restrict__ dinv,
                         const float* __restrict__ Wo, const float* __restrict__ bo,
                         float* __restrict__ out, int n) {
    __shared__ float Ws[64 * 40];
    __shared__ float bs[40];
    __shared__ float h2s[16][68];          // row stride 68 -> quarters hit distinct banks
    for (int i = threadIdx.x; i < 64 * 40; i += 256) Ws[i] = Wo[i];
    if (threadIdx.x < 40) bs[threadIdx.x] = bo[threadIdx.x];

    const int tq = threadIdx.x >> 4;
    const int c  = threadIdx.x & 15;
    const int node = blockIdx.x * 16 + tq;
    if (node < n) {
        const float dn = dinv[node];
        uint2 sv = g2[(size_t)node * 16 + c];
        float a0 = bf_lo(sv.x), a1 = bf_hi(sv.x), a2 = bf_lo(sv.y), a3 = bf_hi(sv.y);
        int j = rs[node] >> 2;
        const int jend = re[node] >> 2;
        const int4* ip = (const int4*)srcids;
        if (j < jend) {
            int4 idx = ip[j];
            for (++j; j < jend; ++j) {
                uint2 v0 = g2[(size_t)idx.x * 16 + c];
                uint2 v1 = g2[(size_t)idx.y * 16 + c];
                uint2 v2 = g2[(size_t)idx.z * 16 + c];
                uint2 v3 = g2[(size_t)idx.w * 16 + c];
                int4 nxt = ip[j];
                a0 += (bf_lo(v0.x) + bf_lo(v1.x)) + (bf_lo(v2.x) + bf_lo(v3.x));
                a1 += (bf_hi(v0.x) + bf_hi(v1.x)) + (bf_hi(v2.x) + bf_hi(v3.x));
                a2 += (bf_lo(v0.y) + bf_lo(v1.y)) + (bf_lo(v2.y) + bf_lo(v3.y));
                a3 += (bf_hi(v0.y) + bf_hi(v1.y)) + (bf_hi(v2.y) + bf_hi(v3.y));
                idx = nxt;
            }
            uint2 v0 = g2[(size_t)idx.x * 16 + c];
            uint2 v1 = g2[(size_t)idx.y * 16 + c];
            uint2 v2 = g2[(size_t)idx.z * 16 + c];
            uint2 v3 = g2[(size_t)idx.w * 16 + c];
            a0 += (bf_lo(v0.x) + bf_lo(v1.x)) + (bf_lo(v2.x) + bf_lo(v3.x));
            a1 += (bf_hi(v0.x) + bf_hi(v1.x)) + (bf_hi(v2.x) + bf_hi(v3.x));
            a2 += (bf_lo(v0.y) + bf_lo(v1.y)) + (bf_lo(v2.y) + bf_lo(v3.y));
            a3 += (bf_hi(v0.y) + bf_hi(v1.y)) + (bf_hi(v2.y) + bf_hi(v3.y));
        }
        float4 bb = bias[c];
        float4 hv = { a0 * dn + bb.x, a1 * dn + bb.y, a2 * dn + bb.z, a3 * dn + bb.w };
        *(float4*)&h2s[tq][c * 4] = hv;
    }
    __syncthreads();

    if (node < n) {
        const int j2 = (c < 8) ? (c + 32) : 39;        // duplicate for c>=8, discarded
        float l0 = bs[c], l1 = bs[c + 16], l2 = bs[j2];
#pragma unroll 8
        for (int k = 0; k < 64; k++) {
            float hk = h2s[tq][k];
            l0 = fmaf(hk, Ws[k * 40 + c], l0);
            l1 = fmaf(hk, Ws[k * 40 + c + 16], l1);
            l2 = fmaf(hk, Ws[k * 40 + j2], l2);
        }
        float m = fmaxf(fmaxf(l0, l1), (c < 8) ? l2 : -3.0e38f);
#pragma unroll
        for (int o = 1; o < 16; o <<= 1) m = fmaxf(m, __shfl_xor(m, o));
        float s = expf(l0 - m) + expf(l1 - m) + ((c < 8) ? expf(l2 - m) : 0.f);
#pragma unroll
        for (int o = 1; o < 16; o <<= 1) s += __shfl_xor(s, o);
        float lse = m + logf(s);
        float* op = out + (size_t)node * 40;
        op[c] = l0 - lse;
        op[c + 16] = l1 - lse;
        if (c < 8) op[c + 32] = l2 - lse;
    }
}

extern "C" void kernel_launch(void* const* d_in, const int* in_sizes, int n_in,
                              void* d_out, int out_size, void* d_ws, size_t ws_size,
                              hipStream_t stream) {
    const float* x  = (const float*)d_in[0];
    const int*   ei = (const int*)d_in[1];
    const float* W1 = (const float*)d_in[2];
    const float* b1 = (const float*)d_in[3];
    const float* W2 = (const float*)d_in[4];
    const float* b2 = (const float*)d_in[5];
    const float* Wo = (const float*)d_in[6];
    const float* bo = (const float*)d_in[7];
    float* out = (float*)d_out;

    const int HID  = in_sizes[3];           // 128
    const int IN   = in_sizes[2] / HID;     // 256
    const int HID1 = in_sizes[5];           // 64
    const int N = in_sizes[0] / IN;         // 100000
    const int E = in_sizes[1] / 2;          // 1600000
    const int* src = ei;
    const int* dst = ei + E;

    const int R2 = (N + NB2 - 1) / NB2;     // 391
    const int bcap2 = E / NB2 + 2048;       // 8298 (~26 sigma)
    const int sreg  = (bcap2 + 3 * R2 + 32 + 3) & ~3;   // region stride, %4==0 (alignment invariant)

    char* ws = (char*)d_ws;
    size_t off = 0;
    auto alloc = [&](size_t bytes) -> void* {
        void* p = ws + off;
        off += (bytes + 255) / 256 * 256;
        return p;
    };
    float* dinv   = (float*)alloc((size_t)N * 4);
    int*   rs     = (int*)alloc((size_t)N * 4);
    int*   re     = (int*)alloc((size_t)N * 4);
    int*   bcur   = (int*)alloc(NB2 * 4);
    int*   srcids = (int*)alloc((size_t)NB2 * sreg * 4);   // ~9.7 MB
    u16*   W1t    = (u16*)alloc((size_t)IN * HID * 2);     // [128][256] bf16
    u16*   W2t    = (u16*)alloc((size_t)HID * HID1 * 2);   // [64][128] bf16
    // shared region: bp2 (CSR build) -> g1 (gemm1/agg128); strictly sequential
    size_t bp2Bytes = (size_t)NB2 * bcap2 * 8;             // ~17 MB
    size_t gBytes = (size_t)(N + 1) * HID * 2;             // 25.6 MB (+ sentinel row)
    size_t sharedBytes = (gBytes > bp2Bytes) ? gBytes : bp2Bytes;
    char*  shared = (char*)alloc(sharedBytes);
    int2*  bp2    = (int2*)shared;
    u16*   g1     = (u16*)shared;                          // bf16 [N+1][128]
    u16*   h1     = (u16*)alloc((size_t)N * HID * 2);      // bf16 [N][128]
    u16*   g2     = (u16*)alloc((size_t)(N + 1) * HID1 * 2); // bf16 [N+1][64]

    // ---- CSR build: single-pass 256-way routing, padded rows ----
    hipMemsetAsync(bcur, 0, NB2 * 4, stream);
    const int nchunk = (E + CHUNK - 1) / CHUNK;            // 196
    route<<<nchunk, 256, 0, stream>>>(src, dst, E, R2, bcur, bp2, bcap2);
    build_csr<<<NB2, 256, 0, stream>>>(bp2, bcur, bcap2, sreg, R2, N, rs, re, dinv, srcids);
    zero_pad<<<1, 64, 0, stream>>>((u32*)g1, (u32*)g2, N);

    // weights -> bf16 transposed
    conv_w2<<<(IN * HID + HID * HID1 + 255) / 256, 256, 0, stream>>>(
        W1, W1t, IN, HID, W2, W2t, HID, HID1);

    const int gblocks = (N + 127) / 128;
    // layer 1: g1 = bf16((x @ W1) * dinv); h1 = bf16(relu(agg(g1)*dinv + b1))
    gemm_mfma<256, 128, 4, 4, 2, 2, false><<<gblocks, 256, 0, stream>>>(x, W1t, dinv, g1, N);
    agg128<<<(N + 15) / 16, 256, 0, stream>>>((const uint4*)g1, (const float4*)b1,
                                              rs, re, srcids, dinv, (uint4*)h1, N);

    // layer 2: g2 = bf16((h1 @ W2) * dinv); out = log_softmax((agg(g2)*dinv + b2) @ Wo + bo)
    gemm_mfma<128, 64, 2, 4, 4, 1, true><<<gblocks, 256, 0, stream>>>(h1, W2t, dinv, g2, N);
    agg64out<<<(N + 15) / 16, 256, 0, stream>>>((const uint2*)g2, (const float4*)b2,
                                                rs, re, srcids, dinv, Wo, bo, out, N);

    (void)ws_size; (void)n_in; (void)out_size; (void)HID1;
}